// Round 1
// baseline (2214.022 us; speedup 1.0000x reference)
//
#include <hip/hip_runtime.h>
#include <hip/hip_bf16.h>

// Fused tracking head, fp32-vector baseline (round 1: correctness + structure).
// ws layout (needs ~62.6 MB):
//   fiT  [B][576][256] f32   @ 0          (pooled init_embed, transposed)
//   si   [B][2][576]   f32   @ 4,718,592
//   hmid [B][128][9216] bf16 @ 4,755,456  (conv1 output)
//   hcat [B][264][9216] bf16 @ 23,629,824 (concat conv1 input)

typedef __hip_bfloat16 bf16;

constexpr int B_  = 8;
constexpr int C_  = 256;
constexpr int H_  = 96;
constexpr int W_  = 96;
constexpr int HW_ = H_ * W_;       // 9216
constexpr int PW_ = 24;
constexpr int KP_ = 576;           // pooled positions
constexpr int C1I = 264;
constexpr int C1O = 128;

__device__ __forceinline__ void store_bf16x4(bf16* p, float4 v) {
    bf16 t0 = __float2bfloat16(v.x), t1 = __float2bfloat16(v.y);
    bf16 t2 = __float2bfloat16(v.z), t3 = __float2bfloat16(v.w);
    ushort4 u;
    u.x = *(const unsigned short*)&t0; u.y = *(const unsigned short*)&t1;
    u.z = *(const unsigned short*)&t2; u.w = *(const unsigned short*)&t3;
    *reinterpret_cast<ushort4*>(p) = u;
}

// ---------------------------------------------------------------- pool ----
__global__ __launch_bounds__(256)
void pool_kernel(const float* __restrict__ init_embed,
                 const float* __restrict__ init_seg,
                 float* __restrict__ fiT,      // [B][KP][C]
                 float* __restrict__ si)       // [B][2][KP]
{
    int idx = blockIdx.x * blockDim.x + threadIdx.x;
    int total = B_ * (C_ + 2) * KP_;
    if (idx >= total) return;
    int k  = idx % KP_;
    int ch = (idx / KP_) % (C_ + 2);
    int b  = idx / (KP_ * (C_ + 2));
    int ph = k / PW_, pw = k % PW_;
    const float* src = (ch < C_)
        ? (init_embed + (((size_t)b * C_ + ch) * H_ + ph * 4) * W_ + pw * 4)
        : (init_seg   + (((size_t)b * 2 + (ch - C_)) * H_ + ph * 4) * W_ + pw * 4);
    float s = 0.f;
    #pragma unroll
    for (int r = 0; r < 4; r++) {
        float4 v = *reinterpret_cast<const float4*>(src + r * W_);
        s += v.x + v.y + v.z + v.w;
    }
    s *= (1.f / 16.f);
    if (ch < C_) fiT[((size_t)b * KP_ + k) * C_ + ch] = s;
    else         si[((size_t)b * 2 + (ch - C_)) * KP_ + k] = s;
}

// ---------------------------------------------------------------- pack ----
__global__ __launch_bounds__(256)
void pack_dec_kernel(const float* __restrict__ cur_decode, bf16* __restrict__ hcat)
{
    int idx = blockIdx.x * blockDim.x + threadIdx.x;
    int total = B_ * C_ * HW_ / 4;
    if (idx >= total) return;
    int px4 = idx % (HW_ / 4);
    int c   = (idx / (HW_ / 4)) % C_;
    int b   = idx / (HW_ / 4 * C_);
    float4 v = reinterpret_cast<const float4*>(cur_decode)[idx];
    store_bf16x4(hcat + ((size_t)b * C1I + c) * HW_ + px4 * 4, v);
}

__global__ __launch_bounds__(256)
void pack_seg_kernel(const float* __restrict__ init_seg,
                     const float* __restrict__ prev_seg, bf16* __restrict__ hcat)
{
    int idx = blockIdx.x * blockDim.x + threadIdx.x;
    int half = B_ * 2 * HW_ / 4;
    if (idx >= 2 * half) return;
    const float* src = (idx < half) ? init_seg : prev_seg;
    int cbase = (idx < half) ? 258 : 262;
    int i = (idx < half) ? idx : idx - half;
    int px4 = i % (HW_ / 4);
    int s   = (i / (HW_ / 4)) % 2;
    int b   = i / (HW_ / 4 * 2);
    float4 v = reinterpret_cast<const float4*>(src)[i];
    store_bf16x4(hcat + ((size_t)b * C1I + cbase + s) * HW_ + px4 * 4, v);
}

// ---------------------------------------------------------------- gmap ----
// Per batch: sim = fiT (576x256) @ cur (256x9216), fused max_k over sim*si.
// Block: 256 thr, px tile 128. k-chunk 32 (8 kg x 4), c-chunk 32.
// Thread t: kg=t>>5 (4 k rows), pg=t&31 (4 px). acc[4][4].
__global__ __launch_bounds__(256)
void gmap_kernel(const float* __restrict__ cur_embed,
                 const float* __restrict__ fiT,
                 const float* __restrict__ si,
                 bf16* __restrict__ hcat)
{
    __shared__ float fi_s[32][36];     // [cc][k] transposed, pad 36
    __shared__ float cur_s[32][128];   // [cc][px]
    __shared__ float si_s[2][32];
    int b  = blockIdx.y;
    int p0 = blockIdx.x * 128;
    int t  = threadIdx.x;
    int kg = t >> 5, pg = t & 31;
    float best0[4], best1[4];
    #pragma unroll
    for (int i = 0; i < 4; i++) { best0[i] = -INFINITY; best1[i] = -INFINITY; }
    const float* curb = cur_embed + (size_t)b * C_ * HW_;
    const float* fib  = fiT + (size_t)b * KP_ * C_;

    for (int k0 = 0; k0 < KP_; k0 += 32) {
        float acc[4][4];
        #pragma unroll
        for (int j = 0; j < 4; j++)
            #pragma unroll
            for (int i = 0; i < 4; i++) acc[j][i] = 0.f;

        for (int c0 = 0; c0 < C_; c0 += 32) {
            __syncthreads();
            { // stage fi chunk transposed: rows k0..k0+31, cols c0..c0+31
                int rr = t >> 3, c4 = (t & 7) * 4;
                float4 v = *reinterpret_cast<const float4*>(fib + (size_t)(k0 + rr) * C_ + c0 + c4);
                fi_s[c4 + 0][rr] = v.x; fi_s[c4 + 1][rr] = v.y;
                fi_s[c4 + 2][rr] = v.z; fi_s[c4 + 3][rr] = v.w;
            }
            #pragma unroll
            for (int it = 0; it < 4; it++) { // stage cur chunk 32x128
                int f = t + it * 256;
                int r = f >> 5, c4 = (f & 31) * 4;
                float4 v = *reinterpret_cast<const float4*>(curb + (size_t)(c0 + r) * HW_ + p0 + c4);
                *reinterpret_cast<float4*>(&cur_s[r][c4]) = v;
            }
            if (c0 == 0 && t < 64)
                si_s[t >> 5][t & 31] = si[((size_t)b * 2 + (t >> 5)) * KP_ + k0 + (t & 31)];
            __syncthreads();

            #pragma unroll
            for (int cc = 0; cc < 32; cc++) {
                float4 fv = *reinterpret_cast<const float4*>(&fi_s[cc][kg * 4]);
                float4 cu = *reinterpret_cast<const float4*>(&cur_s[cc][pg * 4]);
                acc[0][0] += fv.x * cu.x; acc[0][1] += fv.x * cu.y;
                acc[0][2] += fv.x * cu.z; acc[0][3] += fv.x * cu.w;
                acc[1][0] += fv.y * cu.x; acc[1][1] += fv.y * cu.y;
                acc[1][2] += fv.y * cu.z; acc[1][3] += fv.y * cu.w;
                acc[2][0] += fv.z * cu.x; acc[2][1] += fv.z * cu.y;
                acc[2][2] += fv.z * cu.z; acc[2][3] += fv.z * cu.w;
                acc[3][0] += fv.w * cu.x; acc[3][1] += fv.w * cu.y;
                acc[3][2] += fv.w * cu.z; acc[3][3] += fv.w * cu.w;
            }
        }
        #pragma unroll
        for (int j = 0; j < 4; j++) {
            float s0 = si_s[0][kg * 4 + j], s1 = si_s[1][kg * 4 + j];
            #pragma unroll
            for (int i = 0; i < 4; i++) {
                best0[i] = fmaxf(best0[i], acc[j][i] * s0);
                best1[i] = fmaxf(best1[i], acc[j][i] * s1);
            }
        }
    }
    // reduce max across the 8 kg groups via LDS (reuse cur_s)
    __syncthreads();
    float* red = &cur_s[0][0];   // [2][8][128]
    #pragma unroll
    for (int i = 0; i < 4; i++) {
        red[(0 * 8 + kg) * 128 + pg * 4 + i] = best0[i];
        red[(1 * 8 + kg) * 128 + pg * 4 + i] = best1[i];
    }
    __syncthreads();
    {
        int s = t >> 7, px = t & 127;
        float m = red[(s * 8 + 0) * 128 + px];
        #pragma unroll
        for (int g = 1; g < 8; g++) m = fmaxf(m, red[(s * 8 + g) * 128 + px]);
        hcat[((size_t)b * C1I + 256 + s) * HW_ + p0 + px] = __float2bfloat16(m);
    }
}

// ---------------------------------------------------------------- lmap ----
constexpr int WSTR = 19; // padded window row stride
template<int DSTART, int DCNT>
__device__ __forceinline__ void corr_body(float* acc,
                                          const float (*cur_s)[64],
                                          const float (*prev_s)[16 * WSTR],
                                          int px, int woff)
{
    for (int cc = 0; cc < 32; cc++) {
        float cv = cur_s[cc][px];
        const float* pr = &prev_s[cc][woff];
        #pragma unroll
        for (int i = 0; i < DCNT; i++) {
            int d = DSTART + i;                     // compile-time after unroll
            acc[i] += cv * pr[(d / 9) * WSTR + (d % 9)];
        }
    }
}

__global__ __launch_bounds__(256)
void lmap_kernel(const float* __restrict__ cur_embed,
                 const float* __restrict__ prev_embed,
                 const float* __restrict__ prev_seg,
                 bf16* __restrict__ hcat)
{
    __shared__ float prev_s[32][16 * WSTR];
    __shared__ float cur_s[32][64];
    __shared__ float red[2][4][64];
    int b = blockIdx.y;
    int tile = blockIdx.x;                   // 12x12 tiles of 8x8 px
    int ty0 = (tile / 12) * 8, tx0 = (tile % 12) * 8;
    int t = threadIdx.x;
    int px = t & 63, dg = t >> 6;            // one displacement-group per wave
    int py = px >> 3, lx = px & 7;
    int dstart = dg * 20;
    int dcnt = (dg == 3) ? 21 : 20;

    float acc[21];
    #pragma unroll
    for (int i = 0; i < 21; i++) acc[i] = 0.f;
    const float* curb  = cur_embed + (size_t)b * C_ * HW_;
    const float* prevb = prev_embed + (size_t)b * C_ * HW_;

    for (int c0 = 0; c0 < C_; c0 += 32) {
        __syncthreads();
        #pragma unroll
        for (int it = 0; it < 8; it++) {     // stage cur 32x64
            int f = t + it * 256;
            int r = f >> 6, cl = f & 63;
            int gy = ty0 + (cl >> 3), gx = tx0 + (cl & 7);
            cur_s[r][cl] = curb[(size_t)(c0 + r) * HW_ + gy * W_ + gx];
        }
        #pragma unroll
        for (int it = 0; it < 32; it++) {    // stage prev window 32 x 16x16 (zero-pad)
            int f = t + it * 256;
            int r = f >> 8, wp = f & 255;
            int wy = wp >> 4, wx = wp & 15;
            int gy = ty0 - 4 + wy, gx = tx0 - 4 + wx;
            float v = 0.f;
            if (gy >= 0 && gy < H_ && gx >= 0 && gx < W_)
                v = prevb[(size_t)(c0 + r) * HW_ + gy * W_ + gx];
            prev_s[r][wy * WSTR + wx] = v;
        }
        __syncthreads();
        int woff = py * WSTR + lx;
        switch (dg) {
            case 0: corr_body<0, 20>(acc, cur_s, prev_s, px, woff); break;
            case 1: corr_body<20, 20>(acc, cur_s, prev_s, px, woff); break;
            case 2: corr_body<40, 20>(acc, cur_s, prev_s, px, woff); break;
            default: corr_body<60, 21>(acc, cur_s, prev_s, px, woff); break;
        }
    }
    // epilogue: seg-weight + max over this thread's displacements
    float m0 = -INFINITY, m1 = -INFINITY;
    const float* seg0 = prev_seg + (size_t)b * 2 * HW_;
    const float* seg1 = seg0 + HW_;
    int gy0 = ty0 + py, gx0 = tx0 + lx;
    #pragma unroll
    for (int i = 0; i < 21; i++) {
        if (i < dcnt) {
            int d = dstart + i;
            int gy = gy0 + d / 9 - 4, gx = gx0 + d % 9 - 4;
            float v0 = 0.f, v1 = 0.f;
            if (gy >= 0 && gy < H_ && gx >= 0 && gx < W_) {
                float vv = acc[i] * (1.f / 256.f);
                v0 = vv * seg0[gy * W_ + gx];
                v1 = vv * seg1[gy * W_ + gx];
            }
            m0 = fmaxf(m0, v0); m1 = fmaxf(m1, v1);
        }
    }
    red[0][dg][px] = m0; red[1][dg][px] = m1;
    __syncthreads();
    if (t < 128) {
        int s = t >> 6, p = t & 63;
        float m = fmaxf(fmaxf(red[s][0][p], red[s][1][p]),
                        fmaxf(red[s][2][p], red[s][3][p]));
        int gy = ty0 + (p >> 3), gx = tx0 + (p & 7);
        hcat[((size_t)b * C1I + 260 + s) * HW_ + gy * W_ + gx] = __float2bfloat16(m);
    }
}

// ---------------------------------------------------------------- conv1 ----
// 3x3 SAME, 264->128 + ReLU. Tile: 32 oc x (8x16 px). Thread: 4 oc x 4 px.
constexpr int ICCH = 12;
__global__ __launch_bounds__(256)
void conv1_kernel(const bf16* __restrict__ hcat,
                  const float* __restrict__ W1,
                  const float* __restrict__ b1,
                  bf16* __restrict__ hmid)
{
    __shared__ float in_s[ICCH][10][19];
    __shared__ float w_s[32][ICCH][9];
    int b   = blockIdx.z;
    int oc0 = blockIdx.y * 32;
    int tile = blockIdx.x;                     // 12 x 6
    int y0 = (tile / 6) * 8, x0 = (tile % 6) * 16;
    int t = threadIdx.x;
    int j = t & 31, ocq = t >> 5;
    int r = j >> 2, c4 = (j & 3) * 4;
    float acc[4][4];
    #pragma unroll
    for (int a = 0; a < 4; a++)
        #pragma unroll
        for (int i = 0; i < 4; i++) acc[a][i] = 0.f;
    const bf16* hb = hcat + (size_t)b * C1I * HW_;

    for (int ic0 = 0; ic0 < C1I; ic0 += ICCH) {
        __syncthreads();
        for (int f = t; f < ICCH * 10 * 18; f += 256) {
            int ic = f / 180; int rem = f % 180; int row = rem / 18, col = rem % 18;
            int gy = y0 - 1 + row, gx = x0 - 1 + col;
            float v = 0.f;
            if (gy >= 0 && gy < H_ && gx >= 0 && gx < W_)
                v = __bfloat162float(hb[(size_t)(ic0 + ic) * HW_ + gy * W_ + gx]);
            in_s[ic][row][col] = v;
        }
        for (int f = t; f < 32 * ICCH * 9; f += 256) {
            int o = f / (ICCH * 9); int rem = f % (ICCH * 9);
            w_s[o][rem / 9][rem % 9] = W1[((size_t)(oc0 + o) * C1I + ic0 + rem / 9) * 9 + rem % 9];
        }
        __syncthreads();
        for (int ic = 0; ic < ICCH; ic++) {
            #pragma unroll
            for (int ky = 0; ky < 3; ky++) {
                #pragma unroll
                for (int kx = 0; kx < 3; kx++) {
                    float x0v = in_s[ic][r + ky][c4 + kx + 0];
                    float x1v = in_s[ic][r + ky][c4 + kx + 1];
                    float x2v = in_s[ic][r + ky][c4 + kx + 2];
                    float x3v = in_s[ic][r + ky][c4 + kx + 3];
                    float w0 = w_s[ocq * 4 + 0][ic][ky * 3 + kx];
                    float w1 = w_s[ocq * 4 + 1][ic][ky * 3 + kx];
                    float w2 = w_s[ocq * 4 + 2][ic][ky * 3 + kx];
                    float w3 = w_s[ocq * 4 + 3][ic][ky * 3 + kx];
                    acc[0][0] += w0 * x0v; acc[0][1] += w0 * x1v; acc[0][2] += w0 * x2v; acc[0][3] += w0 * x3v;
                    acc[1][0] += w1 * x0v; acc[1][1] += w1 * x1v; acc[1][2] += w1 * x2v; acc[1][3] += w1 * x3v;
                    acc[2][0] += w2 * x0v; acc[2][1] += w2 * x1v; acc[2][2] += w2 * x2v; acc[2][3] += w2 * x3v;
                    acc[3][0] += w3 * x0v; acc[3][1] += w3 * x1v; acc[3][2] += w3 * x2v; acc[3][3] += w3 * x3v;
                }
            }
        }
    }
    #pragma unroll
    for (int jj = 0; jj < 4; jj++) {
        int oc = oc0 + ocq * 4 + jj;
        float bias = b1[oc];
        float4 v;
        v.x = fmaxf(acc[jj][0] + bias, 0.f);
        v.y = fmaxf(acc[jj][1] + bias, 0.f);
        v.z = fmaxf(acc[jj][2] + bias, 0.f);
        v.w = fmaxf(acc[jj][3] + bias, 0.f);
        store_bf16x4(hmid + ((size_t)b * C1O + oc) * HW_ + (y0 + r) * W_ + x0 + c4, v);
    }
}

// ---------------------------------------------------------------- conv2 ----
__global__ __launch_bounds__(256)
void conv2_kernel(const bf16* __restrict__ hmid,
                  const float* __restrict__ W2,
                  const float* __restrict__ b2,
                  float* __restrict__ out)
{
    __shared__ float in_s[16][18 * 19];
    __shared__ float w2_s[2][128 * 9];
    int b = blockIdx.y;
    int tile = blockIdx.x;                     // 6x6 tiles of 16x16 px
    int y0 = (tile / 6) * 16, x0 = (tile % 6) * 16;
    int t = threadIdx.x;
    int r = t >> 4, c = t & 15;
    for (int f = t; f < 2 * 128 * 9; f += 256) w2_s[f / 1152][f % 1152] = W2[f];
    float acc0 = 0.f, acc1 = 0.f;
    const bf16* hb = hmid + (size_t)b * C1O * HW_;
    for (int ic0 = 0; ic0 < 128; ic0 += 16) {
        __syncthreads();
        for (int f = t; f < 16 * 18 * 18; f += 256) {
            int ic = f / 324; int rem = f % 324; int row = rem / 18, col = rem % 18;
            int gy = y0 - 1 + row, gx = x0 - 1 + col;
            float v = 0.f;
            if (gy >= 0 && gy < H_ && gx >= 0 && gx < W_)
                v = __bfloat162float(hb[(size_t)(ic0 + ic) * HW_ + gy * W_ + gx]);
            in_s[ic][row * 19 + col] = v;
        }
        __syncthreads();
        for (int ic = 0; ic < 16; ic++) {
            #pragma unroll
            for (int ky = 0; ky < 3; ky++) {
                #pragma unroll
                for (int kx = 0; kx < 3; kx++) {
                    float x = in_s[ic][(r + ky) * 19 + c + kx];
                    int wk = (ic0 + ic) * 9 + ky * 3 + kx;
                    acc0 += x * w2_s[0][wk];
                    acc1 += x * w2_s[1][wk];
                }
            }
        }
    }
    int py = (y0 + r) * W_ + x0 + c;
    out[((size_t)b * 2 + 0) * HW_ + py] = acc0 + b2[0];
    out[((size_t)b * 2 + 1) * HW_ + py] = acc1 + b2[1];
}

// ---------------------------------------------------------------- launch ----
extern "C" void kernel_launch(void* const* d_in, const int* in_sizes, int n_in,
                              void* d_out, int out_size, void* d_ws, size_t ws_size,
                              hipStream_t stream)
{
    const float* cur_embed  = (const float*)d_in[0];
    const float* cur_decode = (const float*)d_in[1];
    const float* init_embed = (const float*)d_in[2];
    const float* init_seg   = (const float*)d_in[3];
    const float* prev_embed = (const float*)d_in[4];
    const float* prev_seg   = (const float*)d_in[5];
    const float* W1 = (const float*)d_in[6];
    const float* b1 = (const float*)d_in[7];
    const float* W2 = (const float*)d_in[8];
    const float* b2 = (const float*)d_in[9];
    float* out = (float*)d_out;

    char* ws = (char*)d_ws;
    float* fiT = (float*)ws;                       // 4,718,592 B
    float* si  = (float*)(ws + 4718592);           //    36,864 B
    bf16* hmid = (bf16*)(ws + 4755456);            // 18,874,368 B
    bf16* hcat = (bf16*)(ws + 23629824);           // 38,928,384 B (total 62.6 MB)

    { int total = B_ * (C_ + 2) * KP_;
      pool_kernel<<<(total + 255) / 256, 256, 0, stream>>>(init_embed, init_seg, fiT, si); }
    { int total = B_ * C_ * HW_ / 4;
      pack_dec_kernel<<<(total + 255) / 256, 256, 0, stream>>>(cur_decode, hcat); }
    { int total = B_ * 2 * HW_ / 4 * 2;
      pack_seg_kernel<<<(total + 255) / 256, 256, 0, stream>>>(init_seg, prev_seg, hcat); }
    { dim3 g(HW_ / 128, B_);
      gmap_kernel<<<g, 256, 0, stream>>>(cur_embed, fiT, si, hcat); }
    { dim3 g(144, B_);
      lmap_kernel<<<g, 256, 0, stream>>>(cur_embed, prev_embed, prev_seg, hcat); }
    { dim3 g(72, 4, B_);
      conv1_kernel<<<g, 256, 0, stream>>>(hcat, W1, b1, hmid); }
    { dim3 g(36, B_);
      conv2_kernel<<<g, 256, 0, stream>>>(hmid, W2, b2, out); }
}

// Round 2
// 1173.373 us; speedup vs baseline: 1.8869x; 1.8869x over previous
//
#include <hip/hip_runtime.h>
#include <hip/hip_bf16.h>

// Round 2: MFMA for conv1 (implicit GEMM over padded-NHWC) and gmap (GEMM + fused max).
// ws layout (61.9 MB total, aliased; proven-safe budget 62.6 MB):
//   [0, 41,799,680)          hcat_pad bf16 [8][98][98][272] (+1KB slack)   -- ALSO cur_bf bf16 [8][9216][256] (dead before memset)
//   [41,799,680, 60,674,048) hmid bf16 [8][128][9216]                      -- ALSO fiT_bf [8][640][256] bf16 + si [8][2][640] f32 (dead before conv1)
//   [60,674,048, 61,337,600) W1bf bf16 [81][128][32]
//   [61,337,600, 61,927,424) gmap_out f32 [8][2][9216]

typedef __hip_bfloat16 bf16;
typedef __attribute__((ext_vector_type(8))) short short8;
typedef __attribute__((ext_vector_type(4))) float f32x4;

constexpr int B_  = 8;
constexpr int C_  = 256;
constexpr int H_  = 96;
constexpr int W_  = 96;
constexpr int HW_ = H_ * W_;       // 9216
constexpr int PW_ = 24;
constexpr int KP_ = 576;           // real pooled positions
constexpr int KPP = 640;           // padded to 5*128
constexpr int HP_ = 98;            // padded spatial
constexpr int HPW = HP_ * HP_;     // 9604
constexpr int CH_ = 272;           // padded channels in hcat (264 real)
constexpr int C1O = 128;

__device__ __forceinline__ unsigned short bfb(float f) {
    bf16 h = __float2bfloat16(f);
    return *reinterpret_cast<unsigned short*>(&h);
}

// ------------------------------------------------------------ W1 convert ----
// W1 [128][264][3][3] f32 -> W1bf [tap*9+icc][128 oc][32 ic] bf16, zero-pad ic>=264
__global__ __launch_bounds__(256)
void w1cvt_kernel(const float* __restrict__ W1, bf16* __restrict__ w1bf)
{
    int idx = blockIdx.x * 256 + threadIdx.x;
    if (idx >= 81 * 128 * 32) return;
    int ic = idx & 31;
    int oc = (idx >> 5) & 127;
    int ks = idx >> 12;            // /4096
    int tap = ks / 9, icc = ks % 9;
    int icg = icc * 32 + ic;
    float v = (icg < 264) ? W1[((size_t)oc * 264 + icg) * 9 + tap] : 0.f;
    w1bf[idx] = __float2bfloat16(v);
}

// ------------------------------------------------------- cur transpose ----
// cur_embed [B][256][9216] f32 -> cur_bf [B][9216][256] bf16
__global__ __launch_bounds__(256)
void tcur_kernel(const float* __restrict__ cur, bf16* __restrict__ curbf)
{
    __shared__ float tile[64][68];
    int b = blockIdx.z, c0 = blockIdx.y * 64, p0 = blockIdx.x * 64;
    int t = threadIdx.x;
    const float* src = cur + ((size_t)b * C_ + c0) * HW_ + p0;
    #pragma unroll
    for (int it = 0; it < 4; it++) {
        int f = t + it * 256;
        int cl = f >> 4, p4 = (f & 15) * 4;
        float4 v = *reinterpret_cast<const float4*>(src + (size_t)cl * HW_ + p4);
        *reinterpret_cast<float4*>(&tile[cl][p4]) = v;
    }
    __syncthreads();
    bf16* dst = curbf + ((size_t)b * HW_ + p0) * 256 + c0;
    #pragma unroll
    for (int it = 0; it < 4; it++) {
        int f = t + it * 256;
        int pl = f >> 4, c4 = (f & 15) * 4;
        ushort4 u;
        u.x = bfb(tile[c4 + 0][pl]); u.y = bfb(tile[c4 + 1][pl]);
        u.z = bfb(tile[c4 + 2][pl]); u.w = bfb(tile[c4 + 3][pl]);
        *reinterpret_cast<ushort4*>(dst + (size_t)pl * 256 + c4) = u;
    }
}

// ---------------------------------------------------------------- pool ----
// init_embed -> fiT_bf [B][640][256] bf16 (zero rows >=576), init_seg -> si [B][2][640] f32
__global__ __launch_bounds__(256)
void pool_kernel(const float* __restrict__ init_embed,
                 const float* __restrict__ init_seg,
                 bf16* __restrict__ fibf, float* __restrict__ si)
{
    int idx = blockIdx.x * 256 + threadIdx.x;
    int total = B_ * (C_ + 2) * KPP;
    if (idx >= total) return;
    int k  = idx % KPP;
    int ch = (idx / KPP) % (C_ + 2);
    int b  = idx / (KPP * (C_ + 2));
    float s = 0.f;
    if (k < KP_) {
        int ph = k / PW_, pw = k % PW_;
        const float* src = (ch < C_)
            ? (init_embed + (((size_t)b * C_ + ch) * H_ + ph * 4) * W_ + pw * 4)
            : (init_seg   + (((size_t)b * 2 + (ch - C_)) * H_ + ph * 4) * W_ + pw * 4);
        #pragma unroll
        for (int r = 0; r < 4; r++) {
            float4 v = *reinterpret_cast<const float4*>(src + r * W_);
            s += v.x + v.y + v.z + v.w;
        }
        s *= (1.f / 16.f);
    }
    if (ch < C_) fibf[((size_t)b * KPP + k) * C_ + ch] = __float2bfloat16(s);
    else         si[(size_t)b * 2 * KPP + (ch - C_) * KPP + k] = s;
}

// ---------------------------------------------------------------- gmap ----
// D[kp][px] = fiT_bf x cur_bf^T, fused max over kp of D*si. 2 waves (128 thr),
// wave tile 64kp x 64px, block = 128kp-chunk x 64px, 5 m-chunks.
__global__ __launch_bounds__(128)
void gmap_mfma(const bf16* __restrict__ curbf, const bf16* __restrict__ fibf,
               const float* __restrict__ si, float* __restrict__ gout)
{
    __shared__ float bred[2][2][64];
    int b = blockIdx.y;
    int p0 = blockIdx.x * 64;
    int t = threadIdx.x, lane = t & 63, wm = t >> 6;
    int l15 = lane & 15, lk = lane >> 4;
    const bf16* cb = curbf + (size_t)b * HW_ * 256;
    const bf16* fb = fibf + (size_t)b * KPP * 256;
    const float* sib = si + (size_t)b * 2 * KPP;
    size_t bo[4];
    #pragma unroll
    for (int nt = 0; nt < 4; nt++)
        bo[nt] = (size_t)(p0 + nt * 16 + l15) * 256 + lk * 8;
    float best[2][4];
    #pragma unroll
    for (int s = 0; s < 2; s++)
        #pragma unroll
        for (int nt = 0; nt < 4; nt++) best[s][nt] = -INFINITY;

    for (int ch = 0; ch < 5; ch++) {
        int kp0 = ch * 128;
        f32x4 acc[4][4] = {};
        for (int kc = 0; kc < 8; kc++) {
            short8 a[4], bbf[4];
            #pragma unroll
            for (int mt = 0; mt < 4; mt++)
                a[mt] = *reinterpret_cast<const short8*>(
                    fb + (size_t)(kp0 + wm * 64 + mt * 16 + l15) * 256 + kc * 32 + lk * 8);
            #pragma unroll
            for (int nt = 0; nt < 4; nt++)
                bbf[nt] = *reinterpret_cast<const short8*>(cb + bo[nt] + kc * 32);
            #pragma unroll
            for (int mt = 0; mt < 4; mt++)
                #pragma unroll
                for (int nt = 0; nt < 4; nt++)
                    acc[mt][nt] = __builtin_amdgcn_mfma_f32_16x16x32_bf16(
                        a[mt], bbf[nt], acc[mt][nt], 0, 0, 0);
        }
        #pragma unroll
        for (int mt = 0; mt < 4; mt++) {
            int rb = kp0 + wm * 64 + mt * 16 + lk * 4;
            float4 s0 = *reinterpret_cast<const float4*>(sib + rb);
            float4 s1 = *reinterpret_cast<const float4*>(sib + KPP + rb);
            const float* s0p = reinterpret_cast<const float*>(&s0);
            const float* s1p = reinterpret_cast<const float*>(&s1);
            #pragma unroll
            for (int nt = 0; nt < 4; nt++)
                #pragma unroll
                for (int r = 0; r < 4; r++) {
                    float v = acc[mt][nt][r];
                    best[0][nt] = fmaxf(best[0][nt], v * s0p[r]);
                    best[1][nt] = fmaxf(best[1][nt], v * s1p[r]);
                }
        }
    }
    #pragma unroll
    for (int s = 0; s < 2; s++)
        #pragma unroll
        for (int nt = 0; nt < 4; nt++) {
            float v = best[s][nt];
            v = fmaxf(v, __shfl_xor(v, 16));
            v = fmaxf(v, __shfl_xor(v, 32));
            if (lk == 0) bred[wm][s][nt * 16 + l15] = v;
        }
    __syncthreads();
    if (t < 128) {
        int s = t >> 6, pxl = t & 63;
        gout[((size_t)b * 2 + s) * HW_ + p0 + pxl] = fmaxf(bred[0][s][pxl], bred[1][s][pxl]);
    }
}

// ---------------------------------------------------------------- packs ----
// cur_decode [B][256][9216] f32 -> hcat_pad[pos][0..255] bf16 (transpose)
__global__ __launch_bounds__(256)
void pack_dec_kernel(const float* __restrict__ dec, bf16* __restrict__ hcat)
{
    __shared__ float tile[64][68];
    int b = blockIdx.z, c0 = blockIdx.y * 64, p0 = blockIdx.x * 64;
    int t = threadIdx.x;
    const float* src = dec + ((size_t)b * C_ + c0) * HW_ + p0;
    #pragma unroll
    for (int it = 0; it < 4; it++) {
        int f = t + it * 256;
        int cl = f >> 4, p4 = (f & 15) * 4;
        float4 v = *reinterpret_cast<const float4*>(src + (size_t)cl * HW_ + p4);
        *reinterpret_cast<float4*>(&tile[cl][p4]) = v;
    }
    __syncthreads();
    #pragma unroll
    for (int it = 0; it < 4; it++) {
        int f = t + it * 256;
        int pl = f >> 4, c4 = (f & 15) * 4;
        int p = p0 + pl;
        int y = p / 96, x = p % 96;
        int pos = (y + 1) * HP_ + x + 1;
        ushort4 u;
        u.x = bfb(tile[c4 + 0][pl]); u.y = bfb(tile[c4 + 1][pl]);
        u.z = bfb(tile[c4 + 2][pl]); u.w = bfb(tile[c4 + 3][pl]);
        *reinterpret_cast<ushort4*>(hcat + ((size_t)b * HPW + pos) * CH_ + c0 + c4) = u;
    }
}

// gmap_out + init_seg -> ch 256..259 ; prev_seg -> ch 262..263
__global__ __launch_bounds__(256)
void pack_small_kernel(const float* __restrict__ gout,
                       const float* __restrict__ init_seg,
                       const float* __restrict__ prev_seg,
                       bf16* __restrict__ hcat)
{
    int idx = blockIdx.x * 256 + threadIdx.x;
    if (idx >= B_ * HW_) return;
    int b = idx / HW_, p = idx % HW_;
    int y = p / 96, x = p % 96;
    int pos = (y + 1) * HP_ + x + 1;
    bf16* dst = hcat + ((size_t)b * HPW + pos) * CH_;
    float g0 = gout[((size_t)b * 2 + 0) * HW_ + p];
    float g1 = gout[((size_t)b * 2 + 1) * HW_ + p];
    float i0 = init_seg[((size_t)b * 2 + 0) * HW_ + p];
    float i1 = init_seg[((size_t)b * 2 + 1) * HW_ + p];
    float q0 = prev_seg[((size_t)b * 2 + 0) * HW_ + p];
    float q1 = prev_seg[((size_t)b * 2 + 1) * HW_ + p];
    ushort4 u; u.x = bfb(g0); u.y = bfb(g1); u.z = bfb(i0); u.w = bfb(i1);
    *reinterpret_cast<ushort4*>(dst + 256) = u;
    unsigned int pr = (unsigned int)bfb(q0) | ((unsigned int)bfb(q1) << 16);
    *reinterpret_cast<unsigned int*>(dst + 262) = pr;
}

// ---------------------------------------------------------------- lmap ----
constexpr int WSTR = 19;
template<int DSTART, int DCNT>
__device__ __forceinline__ void corr_body(float* acc,
                                          const float (*cur_s)[64],
                                          const float (*prev_s)[16 * WSTR],
                                          int px, int woff)
{
    for (int cc = 0; cc < 32; cc++) {
        float cv = cur_s[cc][px];
        const float* pr = &prev_s[cc][woff];
        #pragma unroll
        for (int i = 0; i < DCNT; i++) {
            int d = DSTART + i;
            acc[i] += cv * pr[(d / 9) * WSTR + (d % 9)];
        }
    }
}

__global__ __launch_bounds__(256)
void lmap_kernel(const float* __restrict__ cur_embed,
                 const float* __restrict__ prev_embed,
                 const float* __restrict__ prev_seg,
                 bf16* __restrict__ hcat)
{
    __shared__ float prev_s[32][16 * WSTR];
    __shared__ float cur_s[32][64];
    __shared__ float red[2][4][64];
    int b = blockIdx.y;
    int tile = blockIdx.x;
    int ty0 = (tile / 12) * 8, tx0 = (tile % 12) * 8;
    int t = threadIdx.x;
    int px = t & 63, dg = t >> 6;
    int py = px >> 3, lx = px & 7;
    int dstart = dg * 20;
    int dcnt = (dg == 3) ? 21 : 20;

    float acc[21];
    #pragma unroll
    for (int i = 0; i < 21; i++) acc[i] = 0.f;
    const float* curb  = cur_embed + (size_t)b * C_ * HW_;
    const float* prevb = prev_embed + (size_t)b * C_ * HW_;

    for (int c0 = 0; c0 < C_; c0 += 32) {
        __syncthreads();
        #pragma unroll
        for (int it = 0; it < 8; it++) {
            int f = t + it * 256;
            int r = f >> 6, cl = f & 63;
            int gy = ty0 + (cl >> 3), gx = tx0 + (cl & 7);
            cur_s[r][cl] = curb[(size_t)(c0 + r) * HW_ + gy * W_ + gx];
        }
        #pragma unroll
        for (int it = 0; it < 32; it++) {
            int f = t + it * 256;
            int r = f >> 8, wp = f & 255;
            int wy = wp >> 4, wx = wp & 15;
            int gy = ty0 - 4 + wy, gx = tx0 - 4 + wx;
            float v = 0.f;
            if (gy >= 0 && gy < H_ && gx >= 0 && gx < W_)
                v = prevb[(size_t)(c0 + r) * HW_ + gy * W_ + gx];
            prev_s[r][wy * WSTR + wx] = v;
        }
        __syncthreads();
        int woff = py * WSTR + lx;
        switch (dg) {
            case 0: corr_body<0, 20>(acc, cur_s, prev_s, px, woff); break;
            case 1: corr_body<20, 20>(acc, cur_s, prev_s, px, woff); break;
            case 2: corr_body<40, 20>(acc, cur_s, prev_s, px, woff); break;
            default: corr_body<60, 21>(acc, cur_s, prev_s, px, woff); break;
        }
    }
    float m0 = -INFINITY, m1 = -INFINITY;
    const float* seg0 = prev_seg + (size_t)b * 2 * HW_;
    const float* seg1 = seg0 + HW_;
    int gy0 = ty0 + py, gx0 = tx0 + lx;
    #pragma unroll
    for (int i = 0; i < 21; i++) {
        if (i < dcnt) {
            int d = dstart + i;
            int gy = gy0 + d / 9 - 4, gx = gx0 + d % 9 - 4;
            float v0 = 0.f, v1 = 0.f;
            if (gy >= 0 && gy < H_ && gx >= 0 && gx < W_) {
                float vv = acc[i] * (1.f / 256.f);
                v0 = vv * seg0[gy * W_ + gx];
                v1 = vv * seg1[gy * W_ + gx];
            }
            m0 = fmaxf(m0, v0); m1 = fmaxf(m1, v1);
        }
    }
    red[0][dg][px] = m0; red[1][dg][px] = m1;
    __syncthreads();
    if (t < 128) {
        int s = t >> 6, p = t & 63;
        float m = fmaxf(fmaxf(red[s][0][p], red[s][1][p]),
                        fmaxf(red[s][2][p], red[s][3][p]));
        int gy = ty0 + (p >> 3), gx = tx0 + (p & 7);
        int pos = (gy + 1) * HP_ + gx + 1;
        hcat[((size_t)b * HPW + pos) * CH_ + 260 + s] = __float2bfloat16(m);
    }
}

// ---------------------------------------------------------------- conv1 ----
// Implicit GEMM over padded NHWC: D[oc][px] = sum_{tap,ic} W1bf x hcat.
// 2 waves (128 thr): wave tile 64oc x 64px, block 128oc x 64px. No LDS, no barriers.
__global__ __launch_bounds__(128)
void conv1_mfma(const bf16* __restrict__ hcat, const bf16* __restrict__ w1bf,
                const float* __restrict__ b1, bf16* __restrict__ hmid)
{
    int b = blockIdx.y;
    int p0 = blockIdx.x * 64;
    int t = threadIdx.x, lane = t & 63, wm = t >> 6;
    int l15 = lane & 15, lk = lane >> 4;
    const bf16* hb = hcat + (size_t)b * HPW * CH_;
    size_t boff[4];
    #pragma unroll
    for (int nt = 0; nt < 4; nt++) {
        int p = p0 + nt * 16 + l15;
        int y = p / 96, x = p % 96;
        boff[nt] = (size_t)(y * HP_ + x) * CH_ + lk * 8;
    }
    int aocbase = wm * 64 + l15;
    f32x4 acc[4][4] = {};

    for (int tap = 0; tap < 9; tap++) {
        int ky = tap / 3, kx = tap % 3;
        size_t toff = (size_t)(ky * HP_ + kx) * CH_;
        for (int icc = 0; icc < 9; icc++) {
            short8 a[4], bbf[4];
            const bf16* wp = w1bf + (size_t)(tap * 9 + icc) * 4096;
            #pragma unroll
            for (int mt = 0; mt < 4; mt++)
                a[mt] = *reinterpret_cast<const short8*>(
                    wp + (aocbase + mt * 16) * 32 + lk * 8);
            #pragma unroll
            for (int nt = 0; nt < 4; nt++)
                bbf[nt] = *reinterpret_cast<const short8*>(hb + boff[nt] + toff + icc * 32);
            #pragma unroll
            for (int mt = 0; mt < 4; mt++)
                #pragma unroll
                for (int nt = 0; nt < 4; nt++)
                    acc[mt][nt] = __builtin_amdgcn_mfma_f32_16x16x32_bf16(
                        a[mt], bbf[nt], acc[mt][nt], 0, 0, 0);
        }
    }
    bf16* hm = hmid + (size_t)b * C1O * HW_;
    #pragma unroll
    for (int mt = 0; mt < 4; mt++) {
        int ocb = wm * 64 + mt * 16 + lk * 4;
        float4 bias = *reinterpret_cast<const float4*>(b1 + ocb);
        const float* bp = reinterpret_cast<const float*>(&bias);
        #pragma unroll
        for (int nt = 0; nt < 4; nt++) {
            int p = p0 + nt * 16 + l15;
            #pragma unroll
            for (int r = 0; r < 4; r++) {
                float v = fmaxf(acc[mt][nt][r] + bp[r], 0.f);
                hm[(size_t)(ocb + r) * HW_ + p] = __float2bfloat16(v);
            }
        }
    }
}

// ---------------------------------------------------------------- conv2 ----
__global__ __launch_bounds__(256)
void conv2_kernel(const bf16* __restrict__ hmid,
                  const float* __restrict__ W2,
                  const float* __restrict__ b2,
                  float* __restrict__ out)
{
    __shared__ float in_s[16][18 * 19];
    __shared__ float w2_s[2][128 * 9];
    int b = blockIdx.y;
    int tile = blockIdx.x;
    int y0 = (tile / 6) * 16, x0 = (tile % 6) * 16;
    int t = threadIdx.x;
    int r = t >> 4, c = t & 15;
    for (int f = t; f < 2 * 128 * 9; f += 256) w2_s[f / 1152][f % 1152] = W2[f];
    float acc0 = 0.f, acc1 = 0.f;
    const bf16* hb = hmid + (size_t)b * C1O * HW_;
    for (int ic0 = 0; ic0 < 128; ic0 += 16) {
        __syncthreads();
        for (int f = t; f < 16 * 18 * 18; f += 256) {
            int ic = f / 324; int rem = f % 324; int row = rem / 18, col = rem % 18;
            int gy = y0 - 1 + row, gx = x0 - 1 + col;
            float v = 0.f;
            if (gy >= 0 && gy < H_ && gx >= 0 && gx < W_)
                v = __bfloat162float(hb[(size_t)(ic0 + ic) * HW_ + gy * W_ + gx]);
            in_s[ic][row * 19 + col] = v;
        }
        __syncthreads();
        for (int ic = 0; ic < 16; ic++) {
            #pragma unroll
            for (int ky = 0; ky < 3; ky++) {
                #pragma unroll
                for (int kx = 0; kx < 3; kx++) {
                    float x = in_s[ic][(r + ky) * 19 + c + kx];
                    int wk = (ic0 + ic) * 9 + ky * 3 + kx;
                    acc0 += x * w2_s[0][wk];
                    acc1 += x * w2_s[1][wk];
                }
            }
        }
    }
    int py = (y0 + r) * W_ + x0 + c;
    out[((size_t)b * 2 + 0) * HW_ + py] = acc0 + b2[0];
    out[((size_t)b * 2 + 1) * HW_ + py] = acc1 + b2[1];
}

// ---------------------------------------------------------------- launch ----
extern "C" void kernel_launch(void* const* d_in, const int* in_sizes, int n_in,
                              void* d_out, int out_size, void* d_ws, size_t ws_size,
                              hipStream_t stream)
{
    const float* cur_embed  = (const float*)d_in[0];
    const float* cur_decode = (const float*)d_in[1];
    const float* init_embed = (const float*)d_in[2];
    const float* init_seg   = (const float*)d_in[3];
    const float* prev_embed = (const float*)d_in[4];
    const float* prev_seg   = (const float*)d_in[5];
    const float* W1 = (const float*)d_in[6];
    const float* b1 = (const float*)d_in[7];
    const float* W2 = (const float*)d_in[8];
    const float* b2 = (const float*)d_in[9];
    float* out = (float*)d_out;

    char* ws = (char*)d_ws;
    bf16* hcat  = (bf16*)ws;                          // [8][9604][272] + slack
    bf16* curbf = (bf16*)ws;                          // alias (dead before memset)
    const size_t HCAT_REGION = 41799680;              // 8*9604*272*2 + 1024
    bf16* hmid = (bf16*)(ws + HCAT_REGION);           // [8][128][9216] bf16
    bf16* fibf = (bf16*)(ws + HCAT_REGION);           // alias hmid region
    float* si  = (float*)(ws + HCAT_REGION + 2621440);
    bf16* w1bf = (bf16*)(ws + 60674048);
    float* gout = (float*)(ws + 61337600);

    { int total = 81 * 128 * 32;
      w1cvt_kernel<<<(total + 255) / 256, 256, 0, stream>>>(W1, w1bf); }
    { dim3 g(144, 4, B_);
      tcur_kernel<<<g, 256, 0, stream>>>(cur_embed, curbf); }
    { int total = B_ * (C_ + 2) * KPP;
      pool_kernel<<<(total + 255) / 256, 256, 0, stream>>>(init_embed, init_seg, fibf, si); }
    { dim3 g(144, B_);
      gmap_mfma<<<g, 128, 0, stream>>>(curbf, fibf, si, gout); }
    hipMemsetAsync(ws, 0, HCAT_REGION, stream);       // zero hcat (pads + borders); curbf dead
    { dim3 g(144, 4, B_);
      pack_dec_kernel<<<g, 256, 0, stream>>>(cur_decode, hcat); }
    { int total = B_ * HW_;
      pack_small_kernel<<<(total + 255) / 256, 256, 0, stream>>>(gout, init_seg, prev_seg, hcat); }
    { dim3 g(144, B_);
      lmap_kernel<<<g, 256, 0, stream>>>(cur_embed, prev_embed, prev_seg, hcat); }
    { dim3 g(144, B_);
      conv1_mfma<<<g, 128, 0, stream>>>(hcat, w1bf, b1, hmid); }
    { dim3 g(36, B_);
      conv2_kernel<<<g, 256, 0, stream>>>(hmid, W2, b2, out); }
}

// Round 3
// 486.958 us; speedup vs baseline: 4.5466x; 2.4096x over previous
//
#include <hip/hip_runtime.h>
#include <hip/hip_bf16.h>

// Round 3: lmap -> MFMA Gram-matrix formulation (per 8x8 tile vs 16x16 prev window).
// ws layout (62.52 MB total, aliased; proven-safe budget 62.56 MB):
//   [0, 41,799,680)          hcat_pad bf16 [8][98][98][272] (+1KB slack)   -- ALSO cur_bf bf16 [8][9216][256] (dead before memset)
//   [41,799,680, 60,674,048) hmid bf16 [8][128][9216]
//       -- phase1 alias: fiT_bf [8][640][256] bf16 @ +0, si [8][2][640] f32 @ +2,621,440
//       -- phase2 alias: prevbf bf16 [2][9216][256] @ +0 (per 2-batch group)
//   [60,674,048, 61,337,600) W1bf bf16 [81][128][32]
//   [61,337,600, 61,927,424) gout f32 [8][2][9216]
//   [61,927,424, 62,517,248) lout f32 [8][2][9216]

typedef __hip_bfloat16 bf16;
typedef __attribute__((ext_vector_type(8))) short short8;
typedef __attribute__((ext_vector_type(4))) float f32x4;

constexpr int B_  = 8;
constexpr int C_  = 256;
constexpr int H_  = 96;
constexpr int W_  = 96;
constexpr int HW_ = H_ * W_;       // 9216
constexpr int PW_ = 24;
constexpr int KP_ = 576;           // real pooled positions
constexpr int KPP = 640;           // padded to 5*128
constexpr int HP_ = 98;            // padded spatial
constexpr int HPW = HP_ * HP_;     // 9604
constexpr int CH_ = 272;           // padded channels in hcat (264 real)
constexpr int C1O = 128;

__device__ __forceinline__ unsigned short bfb(float f) {
    bf16 h = __float2bfloat16(f);
    return *reinterpret_cast<unsigned short*>(&h);
}

// ------------------------------------------------------------ W1 convert ----
__global__ __launch_bounds__(256)
void w1cvt_kernel(const float* __restrict__ W1, bf16* __restrict__ w1bf)
{
    int idx = blockIdx.x * 256 + threadIdx.x;
    if (idx >= 81 * 128 * 32) return;
    int ic = idx & 31;
    int oc = (idx >> 5) & 127;
    int ks = idx >> 12;
    int tap = ks / 9, icc = ks % 9;
    int icg = icc * 32 + ic;
    float v = (icg < 264) ? W1[((size_t)oc * 264 + icg) * 9 + tap] : 0.f;
    w1bf[idx] = __float2bfloat16(v);
}

// ------------------------------------------------------- NCHW->NHWC bf16 ----
// src [Z][256][9216] f32 -> dst [Z][9216][256] bf16  (Z = gridDim.z batches)
__global__ __launch_bounds__(256)
void tcur_kernel(const float* __restrict__ cur, bf16* __restrict__ curbf)
{
    __shared__ float tile[64][68];
    int b = blockIdx.z, c0 = blockIdx.y * 64, p0 = blockIdx.x * 64;
    int t = threadIdx.x;
    const float* src = cur + ((size_t)b * C_ + c0) * HW_ + p0;
    #pragma unroll
    for (int it = 0; it < 4; it++) {
        int f = t + it * 256;
        int cl = f >> 4, p4 = (f & 15) * 4;
        float4 v = *reinterpret_cast<const float4*>(src + (size_t)cl * HW_ + p4);
        *reinterpret_cast<float4*>(&tile[cl][p4]) = v;
    }
    __syncthreads();
    bf16* dst = curbf + ((size_t)b * HW_ + p0) * 256 + c0;
    #pragma unroll
    for (int it = 0; it < 4; it++) {
        int f = t + it * 256;
        int pl = f >> 4, c4 = (f & 15) * 4;
        ushort4 u;
        u.x = bfb(tile[c4 + 0][pl]); u.y = bfb(tile[c4 + 1][pl]);
        u.z = bfb(tile[c4 + 2][pl]); u.w = bfb(tile[c4 + 3][pl]);
        *reinterpret_cast<ushort4*>(dst + (size_t)pl * 256 + c4) = u;
    }
}

// ---------------------------------------------------------------- pool ----
__global__ __launch_bounds__(256)
void pool_kernel(const float* __restrict__ init_embed,
                 const float* __restrict__ init_seg,
                 bf16* __restrict__ fibf, float* __restrict__ si)
{
    int idx = blockIdx.x * 256 + threadIdx.x;
    int total = B_ * (C_ + 2) * KPP;
    if (idx >= total) return;
    int k  = idx % KPP;
    int ch = (idx / KPP) % (C_ + 2);
    int b  = idx / (KPP * (C_ + 2));
    float s = 0.f;
    if (k < KP_) {
        int ph = k / PW_, pw = k % PW_;
        const float* src = (ch < C_)
            ? (init_embed + (((size_t)b * C_ + ch) * H_ + ph * 4) * W_ + pw * 4)
            : (init_seg   + (((size_t)b * 2 + (ch - C_)) * H_ + ph * 4) * W_ + pw * 4);
        #pragma unroll
        for (int r = 0; r < 4; r++) {
            float4 v = *reinterpret_cast<const float4*>(src + r * W_);
            s += v.x + v.y + v.z + v.w;
        }
        s *= (1.f / 16.f);
    }
    if (ch < C_) fibf[((size_t)b * KPP + k) * C_ + ch] = __float2bfloat16(s);
    else         si[(size_t)b * 2 * KPP + (ch - C_) * KPP + k] = s;
}

// ---------------------------------------------------------------- gmap ----
__global__ __launch_bounds__(128)
void gmap_mfma(const bf16* __restrict__ curbf, const bf16* __restrict__ fibf,
               const float* __restrict__ si, float* __restrict__ gout)
{
    __shared__ float bred[2][2][64];
    int b = blockIdx.y;
    int p0 = blockIdx.x * 64;
    int t = threadIdx.x, lane = t & 63, wm = t >> 6;
    int l15 = lane & 15, lk = lane >> 4;
    const bf16* cb = curbf + (size_t)b * HW_ * 256;
    const bf16* fb = fibf + (size_t)b * KPP * 256;
    const float* sib = si + (size_t)b * 2 * KPP;
    size_t bo[4];
    #pragma unroll
    for (int nt = 0; nt < 4; nt++)
        bo[nt] = (size_t)(p0 + nt * 16 + l15) * 256 + lk * 8;
    float best[2][4];
    #pragma unroll
    for (int s = 0; s < 2; s++)
        #pragma unroll
        for (int nt = 0; nt < 4; nt++) best[s][nt] = -INFINITY;

    for (int ch = 0; ch < 5; ch++) {
        int kp0 = ch * 128;
        f32x4 acc[4][4] = {};
        for (int kc = 0; kc < 8; kc++) {
            short8 a[4], bbf[4];
            #pragma unroll
            for (int mt = 0; mt < 4; mt++)
                a[mt] = *reinterpret_cast<const short8*>(
                    fb + (size_t)(kp0 + wm * 64 + mt * 16 + l15) * 256 + kc * 32 + lk * 8);
            #pragma unroll
            for (int nt = 0; nt < 4; nt++)
                bbf[nt] = *reinterpret_cast<const short8*>(cb + bo[nt] + kc * 32);
            #pragma unroll
            for (int mt = 0; mt < 4; mt++)
                #pragma unroll
                for (int nt = 0; nt < 4; nt++)
                    acc[mt][nt] = __builtin_amdgcn_mfma_f32_16x16x32_bf16(
                        a[mt], bbf[nt], acc[mt][nt], 0, 0, 0);
        }
        #pragma unroll
        for (int mt = 0; mt < 4; mt++) {
            int rb = kp0 + wm * 64 + mt * 16 + lk * 4;
            float4 s0 = *reinterpret_cast<const float4*>(sib + rb);
            float4 s1 = *reinterpret_cast<const float4*>(sib + KPP + rb);
            const float* s0p = reinterpret_cast<const float*>(&s0);
            const float* s1p = reinterpret_cast<const float*>(&s1);
            #pragma unroll
            for (int nt = 0; nt < 4; nt++)
                #pragma unroll
                for (int r = 0; r < 4; r++) {
                    float v = acc[mt][nt][r];
                    best[0][nt] = fmaxf(best[0][nt], v * s0p[r]);
                    best[1][nt] = fmaxf(best[1][nt], v * s1p[r]);
                }
        }
    }
    #pragma unroll
    for (int s = 0; s < 2; s++)
        #pragma unroll
        for (int nt = 0; nt < 4; nt++) {
            float v = best[s][nt];
            v = fmaxf(v, __shfl_xor(v, 16));
            v = fmaxf(v, __shfl_xor(v, 32));
            if (lk == 0) bred[wm][s][nt * 16 + l15] = v;
        }
    __syncthreads();
    if (t < 128) {
        int s = t >> 6, pxl = t & 63;
        gout[((size_t)b * 2 + s) * HW_ + p0 + pxl] = fmaxf(bred[0][s][pxl], bred[1][s][pxl]);
    }
}

// ---------------------------------------------------------------- lmap ----
// Per 8x8 px tile: Gram G[64 px][256 window px] via MFMA (K=256 ch), then
// seg-weighted 9x9 max scan in LDS. 4 waves: wave wq owns window cols wq*64..+63.
__global__ __launch_bounds__(256)
void lmap_mfma(const bf16* __restrict__ curbf, const bf16* __restrict__ prevbf,
               const float* __restrict__ prev_seg, float* __restrict__ lout, int b0)
{
    constexpr int GSTR = 257;
    constexpr int SEGB = 64 * GSTR;          // 16448
    constexpr int REDB = SEGB + 512;         // 16960
    __shared__ float gl[REDB + 256];         // 68,864 B
    int b = b0 + blockIdx.y;                 // global batch
    const bf16* pb = prevbf + (size_t)blockIdx.y * HW_ * 256;  // local batch
    const bf16* cb = curbf + (size_t)b * HW_ * 256;
    int tile = blockIdx.x;
    int ty0 = (tile / 12) * 8, tx0 = (tile % 12) * 8;
    int t = threadIdx.x, lane = t & 63, wq = t >> 6;
    int l15 = lane & 15, lk = lane >> 4;

    size_t aoff[4];
    #pragma unroll
    for (int mt = 0; mt < 4; mt++) {
        int m = mt * 16 + l15;
        int gpx = (ty0 + (m >> 3)) * W_ + tx0 + (m & 7);
        aoff[mt] = (size_t)gpx * 256 + lk * 8;
    }
    bool pred[4];
    size_t boff[4];
    int gx = tx0 - 4 + l15;
    bool colok = (gx >= 0) && (gx < W_);
    #pragma unroll
    for (int nt = 0; nt < 4; nt++) {
        int gy = ty0 - 4 + wq * 4 + nt;
        pred[nt] = colok && (gy >= 0) && (gy < H_);
        boff[nt] = pred[nt] ? ((size_t)(gy * W_ + gx) * 256 + lk * 8) : 0;
    }

    f32x4 acc[4][4] = {};
    const short8 Z8 = {0, 0, 0, 0, 0, 0, 0, 0};
    for (int kc = 0; kc < 8; kc++) {
        short8 a[4], bb[4];
        #pragma unroll
        for (int mt = 0; mt < 4; mt++)
            a[mt] = *reinterpret_cast<const short8*>(cb + aoff[mt] + kc * 32);
        #pragma unroll
        for (int nt = 0; nt < 4; nt++) {
            short8 v = Z8;
            if (pred[nt]) v = *reinterpret_cast<const short8*>(pb + boff[nt] + kc * 32);
            bb[nt] = v;
        }
        #pragma unroll
        for (int mt = 0; mt < 4; mt++)
            #pragma unroll
            for (int nt = 0; nt < 4; nt++)
                acc[mt][nt] = __builtin_amdgcn_mfma_f32_16x16x32_bf16(
                    a[mt], bb[nt], acc[mt][nt], 0, 0, 0);
    }
    // G -> LDS (row m, col n), f32
    #pragma unroll
    for (int mt = 0; mt < 4; mt++)
        #pragma unroll
        for (int nt = 0; nt < 4; nt++)
            #pragma unroll
            for (int r = 0; r < 4; r++)
                gl[(mt * 16 + lk * 4 + r) * GSTR + wq * 64 + nt * 16 + l15] = acc[mt][nt][r];
    // seg window (pre-scaled by 1/C), zero-padded
    #pragma unroll
    for (int it = 0; it < 2; it++) {
        int f = t + it * 256;                 // [0,512): s = f>>8, wp = f&255
        int s = f >> 8, wp = f & 255;
        int wy = wp >> 4, wx = wp & 15;
        int gy = ty0 - 4 + wy, gxx = tx0 - 4 + wx;
        float v = 0.f;
        if (gy >= 0 && gy < H_ && gxx >= 0 && gxx < W_)
            v = prev_seg[((size_t)b * 2 + s) * HW_ + gy * W_ + gxx] * (1.f / 256.f);
        gl[SEGB + f] = v;
    }
    __syncthreads();
    // scan: thread t -> px m, (seg s, wy-half hh); wave-uniform (s,hh)
    {
        int m = t & 63;
        int sh = t >> 6;
        int s = sh >> 1, hh = sh & 1;
        int py = m >> 3, lx = m & 7;
        const float* gr = gl + m * GSTR;
        const float* sr = gl + SEGB + s * 256;
        float mx = -INFINITY;
        int wr0 = hh * 5, wr1 = hh ? 9 : 5;
        for (int wr = wr0; wr < wr1; ++wr) {
            int base = (py + wr) * 16 + lx;
            #pragma unroll
            for (int wc = 0; wc < 9; ++wc)
                mx = fmaxf(mx, gr[base + wc] * sr[base + wc]);
        }
        gl[REDB + sh * 64 + m] = mx;
    }
    __syncthreads();
    if (t < 128) {
        int s = t >> 6, m = t & 63;
        float v = fmaxf(gl[REDB + (s * 2 + 0) * 64 + m], gl[REDB + (s * 2 + 1) * 64 + m]);
        int gpx = (ty0 + (m >> 3)) * W_ + tx0 + (m & 7);
        lout[((size_t)b * 2 + s) * HW_ + gpx] = v;
    }
}

// ---------------------------------------------------------------- packs ----
__global__ __launch_bounds__(256)
void pack_dec_kernel(const float* __restrict__ dec, bf16* __restrict__ hcat)
{
    __shared__ float tile[64][68];
    int b = blockIdx.z, c0 = blockIdx.y * 64, p0 = blockIdx.x * 64;
    int t = threadIdx.x;
    const float* src = dec + ((size_t)b * C_ + c0) * HW_ + p0;
    #pragma unroll
    for (int it = 0; it < 4; it++) {
        int f = t + it * 256;
        int cl = f >> 4, p4 = (f & 15) * 4;
        float4 v = *reinterpret_cast<const float4*>(src + (size_t)cl * HW_ + p4);
        *reinterpret_cast<float4*>(&tile[cl][p4]) = v;
    }
    __syncthreads();
    #pragma unroll
    for (int it = 0; it < 4; it++) {
        int f = t + it * 256;
        int pl = f >> 4, c4 = (f & 15) * 4;
        int p = p0 + pl;
        int y = p / 96, x = p % 96;
        int pos = (y + 1) * HP_ + x + 1;
        ushort4 u;
        u.x = bfb(tile[c4 + 0][pl]); u.y = bfb(tile[c4 + 1][pl]);
        u.z = bfb(tile[c4 + 2][pl]); u.w = bfb(tile[c4 + 3][pl]);
        *reinterpret_cast<ushort4*>(hcat + ((size_t)b * HPW + pos) * CH_ + c0 + c4) = u;
    }
}

// gmap -> ch 256,257; init_seg -> 258,259; lmap -> 260,261; prev_seg -> 262,263
__global__ __launch_bounds__(256)
void pack_small_kernel(const float* __restrict__ gout,
                       const float* __restrict__ lout,
                       const float* __restrict__ init_seg,
                       const float* __restrict__ prev_seg,
                       bf16* __restrict__ hcat)
{
    int idx = blockIdx.x * 256 + threadIdx.x;
    if (idx >= B_ * HW_) return;
    int b = idx / HW_, p = idx % HW_;
    int y = p / 96, x = p % 96;
    int pos = (y + 1) * HP_ + x + 1;
    bf16* dst = hcat + ((size_t)b * HPW + pos) * CH_;
    float g0 = gout[((size_t)b * 2 + 0) * HW_ + p];
    float g1 = gout[((size_t)b * 2 + 1) * HW_ + p];
    float i0 = init_seg[((size_t)b * 2 + 0) * HW_ + p];
    float i1 = init_seg[((size_t)b * 2 + 1) * HW_ + p];
    float l0 = lout[((size_t)b * 2 + 0) * HW_ + p];
    float l1 = lout[((size_t)b * 2 + 1) * HW_ + p];
    float q0 = prev_seg[((size_t)b * 2 + 0) * HW_ + p];
    float q1 = prev_seg[((size_t)b * 2 + 1) * HW_ + p];
    ushort4 u; u.x = bfb(g0); u.y = bfb(g1); u.z = bfb(i0); u.w = bfb(i1);
    *reinterpret_cast<ushort4*>(dst + 256) = u;
    ushort4 u2; u2.x = bfb(l0); u2.y = bfb(l1); u2.z = bfb(q0); u2.w = bfb(q1);
    *reinterpret_cast<ushort4*>(dst + 260) = u2;
}

// ---------------------------------------------------------------- conv1 ----
__global__ __launch_bounds__(128)
void conv1_mfma(const bf16* __restrict__ hcat, const bf16* __restrict__ w1bf,
                const float* __restrict__ b1, bf16* __restrict__ hmid)
{
    int b = blockIdx.y;
    int p0 = blockIdx.x * 64;
    int t = threadIdx.x, lane = t & 63, wm = t >> 6;
    int l15 = lane & 15, lk = lane >> 4;
    const bf16* hb = hcat + (size_t)b * HPW * CH_;
    size_t boff[4];
    #pragma unroll
    for (int nt = 0; nt < 4; nt++) {
        int p = p0 + nt * 16 + l15;
        int y = p / 96, x = p % 96;
        boff[nt] = (size_t)(y * HP_ + x) * CH_ + lk * 8;
    }
    int aocbase = wm * 64 + l15;
    f32x4 acc[4][4] = {};

    for (int tap = 0; tap < 9; tap++) {
        int ky = tap / 3, kx = tap % 3;
        size_t toff = (size_t)(ky * HP_ + kx) * CH_;
        for (int icc = 0; icc < 9; icc++) {
            short8 a[4], bbf[4];
            const bf16* wp = w1bf + (size_t)(tap * 9 + icc) * 4096;
            #pragma unroll
            for (int mt = 0; mt < 4; mt++)
                a[mt] = *reinterpret_cast<const short8*>(
                    wp + (aocbase + mt * 16) * 32 + lk * 8);
            #pragma unroll
            for (int nt = 0; nt < 4; nt++)
                bbf[nt] = *reinterpret_cast<const short8*>(hb + boff[nt] + toff + icc * 32);
            #pragma unroll
            for (int mt = 0; mt < 4; mt++)
                #pragma unroll
                for (int nt = 0; nt < 4; nt++)
                    acc[mt][nt] = __builtin_amdgcn_mfma_f32_16x16x32_bf16(
                        a[mt], bbf[nt], acc[mt][nt], 0, 0, 0);
        }
    }
    bf16* hm = hmid + (size_t)b * C1O * HW_;
    #pragma unroll
    for (int mt = 0; mt < 4; mt++) {
        int ocb = wm * 64 + mt * 16 + lk * 4;
        float4 bias = *reinterpret_cast<const float4*>(b1 + ocb);
        const float* bp = reinterpret_cast<const float*>(&bias);
        #pragma unroll
        for (int nt = 0; nt < 4; nt++) {
            int p = p0 + nt * 16 + l15;
            #pragma unroll
            for (int r = 0; r < 4; r++) {
                float v = fmaxf(acc[mt][nt][r] + bp[r], 0.f);
                hm[(size_t)(ocb + r) * HW_ + p] = __float2bfloat16(v);
            }
        }
    }
}

// ---------------------------------------------------------------- conv2 ----
__global__ __launch_bounds__(256)
void conv2_kernel(const bf16* __restrict__ hmid,
                  const float* __restrict__ W2,
                  const float* __restrict__ b2,
                  float* __restrict__ out)
{
    __shared__ float in_s[16][18 * 19];
    __shared__ float w2_s[2][128 * 9];
    int b = blockIdx.y;
    int tile = blockIdx.x;
    int y0 = (tile / 6) * 16, x0 = (tile % 6) * 16;
    int t = threadIdx.x;
    int r = t >> 4, c = t & 15;
    for (int f = t; f < 2 * 128 * 9; f += 256) w2_s[f / 1152][f % 1152] = W2[f];
    float acc0 = 0.f, acc1 = 0.f;
    const bf16* hb = hmid + (size_t)b * C1O * HW_;
    for (int ic0 = 0; ic0 < 128; ic0 += 16) {
        __syncthreads();
        for (int f = t; f < 16 * 18 * 18; f += 256) {
            int ic = f / 324; int rem = f % 324; int row = rem / 18, col = rem % 18;
            int gy = y0 - 1 + row, gxx = x0 - 1 + col;
            float v = 0.f;
            if (gy >= 0 && gy < H_ && gxx >= 0 && gxx < W_)
                v = __bfloat162float(hb[(size_t)(ic0 + ic) * HW_ + gy * W_ + gxx]);
            in_s[ic][row * 19 + col] = v;
        }
        __syncthreads();
        for (int ic = 0; ic < 16; ic++) {
            #pragma unroll
            for (int ky = 0; ky < 3; ky++) {
                #pragma unroll
                for (int kx = 0; kx < 3; kx++) {
                    float x = in_s[ic][(r + ky) * 19 + c + kx];
                    int wk = (ic0 + ic) * 9 + ky * 3 + kx;
                    acc0 += x * w2_s[0][wk];
                    acc1 += x * w2_s[1][wk];
                }
            }
        }
    }
    int py = (y0 + r) * W_ + x0 + c;
    out[((size_t)b * 2 + 0) * HW_ + py] = acc0 + b2[0];
    out[((size_t)b * 2 + 1) * HW_ + py] = acc1 + b2[1];
}

// ---------------------------------------------------------------- launch ----
extern "C" void kernel_launch(void* const* d_in, const int* in_sizes, int n_in,
                              void* d_out, int out_size, void* d_ws, size_t ws_size,
                              hipStream_t stream)
{
    const float* cur_embed  = (const float*)d_in[0];
    const float* cur_decode = (const float*)d_in[1];
    const float* init_embed = (const float*)d_in[2];
    const float* init_seg   = (const float*)d_in[3];
    const float* prev_embed = (const float*)d_in[4];
    const float* prev_seg   = (const float*)d_in[5];
    const float* W1 = (const float*)d_in[6];
    const float* b1 = (const float*)d_in[7];
    const float* W2 = (const float*)d_in[8];
    const float* b2 = (const float*)d_in[9];
    float* out = (float*)d_out;

    char* ws = (char*)d_ws;
    bf16* hcat  = (bf16*)ws;
    bf16* curbf = (bf16*)ws;                          // alias (dead before memset)
    const size_t HCAT_REGION = 41799680;
    bf16* hmid   = (bf16*)(ws + HCAT_REGION);
    bf16* fibf   = (bf16*)(ws + HCAT_REGION);         // phase-1 alias
    bf16* prevbf = (bf16*)(ws + HCAT_REGION);         // phase-2 alias (2 batches)
    float* si  = (float*)(ws + HCAT_REGION + 2621440);
    bf16* w1bf = (bf16*)(ws + 60674048);
    float* gout = (float*)(ws + 61337600);
    float* lout = (float*)(ws + 61927424);

    { int total = 81 * 128 * 32;
      w1cvt_kernel<<<(total + 255) / 256, 256, 0, stream>>>(W1, w1bf); }
    { dim3 g(144, 4, B_);
      tcur_kernel<<<g, 256, 0, stream>>>(cur_embed, curbf); }
    { int total = B_ * (C_ + 2) * KPP;
      pool_kernel<<<(total + 255) / 256, 256, 0, stream>>>(init_embed, init_seg, fibf, si); }
    { dim3 g(144, B_);
      gmap_mfma<<<g, 128, 0, stream>>>(curbf, fibf, si, gout); }
    // lmap in 4 groups of 2 batches (prevbf aliases the dead fibf/hmid region)
    for (int g = 0; g < 4; g++) {
        dim3 gt(144, 4, 2);
        tcur_kernel<<<gt, 256, 0, stream>>>(prev_embed + (size_t)g * 2 * C_ * HW_, prevbf);
        dim3 gl(144, 2);
        lmap_mfma<<<gl, 256, 0, stream>>>(curbf, prevbf, prev_seg, lout, g * 2);
    }
    hipMemsetAsync(ws, 0, HCAT_REGION, stream);       // zero hcat; curbf dead
    { dim3 g(144, 4, B_);
      pack_dec_kernel<<<g, 256, 0, stream>>>(cur_decode, hcat); }
    { int total = B_ * HW_;
      pack_small_kernel<<<(total + 255) / 256, 256, 0, stream>>>(gout, lout, init_seg, prev_seg, hcat); }
    { dim3 g(144, B_);
      conv1_mfma<<<g, 128, 0, stream>>>(hcat, w1bf, b1, hmid); }
    { dim3 g(36, B_);
      conv2_kernel<<<g, 256, 0, stream>>>(hmid, W2, b2, out); }
}

// Round 4
// 485.491 us; speedup vs baseline: 4.5604x; 1.0030x over previous
//
#include <hip/hip_runtime.h>
#include <hip/hip_bf16.h>

// Round 4: conv1 -> LDS-staged double-buffered implicit GEMM (4 waves, 128oc x 8x16px);
//          lmap batching 4x2 -> 2x4.
// ws layout (62.52 MB total, aliased; proven-safe budget 62.56 MB):
//   [0, 41,799,680)          hcat_pad bf16 [8][98][98][272] (+1KB slack)   -- ALSO cur_bf bf16 [8][9216][256] (dead before memset)
//   [41,799,680, 60,674,048) hmid bf16 [8][128][9216]
//       -- phase1 alias: fiT_bf [8][640][256] bf16 @ +0, si [8][2][640] f32 @ +2,621,440
//       -- phase2 alias: prevbf bf16 [4][9216][256] @ +0 (per 4-batch group, exactly 18,874,368 B)
//   [60,674,048, 61,337,600) W1bf bf16 [81][128][32]
//   [61,337,600, 61,927,424) gout f32 [8][2][9216]
//   [61,927,424, 62,517,248) lout f32 [8][2][9216]

typedef __hip_bfloat16 bf16;
typedef __attribute__((ext_vector_type(8))) short short8;
typedef __attribute__((ext_vector_type(4))) float f32x4;

constexpr int B_  = 8;
constexpr int C_  = 256;
constexpr int H_  = 96;
constexpr int W_  = 96;
constexpr int HW_ = H_ * W_;       // 9216
constexpr int PW_ = 24;
constexpr int KP_ = 576;
constexpr int KPP = 640;
constexpr int HP_ = 98;
constexpr int HPW = HP_ * HP_;     // 9604
constexpr int CH_ = 272;
constexpr int C1O = 128;

__device__ __forceinline__ unsigned short bfb(float f) {
    bf16 h = __float2bfloat16(f);
    return *reinterpret_cast<unsigned short*>(&h);
}

// ------------------------------------------------------------ W1 convert ----
__global__ __launch_bounds__(256)
void w1cvt_kernel(const float* __restrict__ W1, bf16* __restrict__ w1bf)
{
    int idx = blockIdx.x * 256 + threadIdx.x;
    if (idx >= 81 * 128 * 32) return;
    int ic = idx & 31;
    int oc = (idx >> 5) & 127;
    int ks = idx >> 12;
    int tap = ks / 9, icc = ks % 9;
    int icg = icc * 32 + ic;
    float v = (icg < 264) ? W1[((size_t)oc * 264 + icg) * 9 + tap] : 0.f;
    w1bf[idx] = __float2bfloat16(v);
}

// ------------------------------------------------------- NCHW->NHWC bf16 ----
__global__ __launch_bounds__(256)
void tcur_kernel(const float* __restrict__ cur, bf16* __restrict__ curbf)
{
    __shared__ float tile[64][68];
    int b = blockIdx.z, c0 = blockIdx.y * 64, p0 = blockIdx.x * 64;
    int t = threadIdx.x;
    const float* src = cur + ((size_t)b * C_ + c0) * HW_ + p0;
    #pragma unroll
    for (int it = 0; it < 4; it++) {
        int f = t + it * 256;
        int cl = f >> 4, p4 = (f & 15) * 4;
        float4 v = *reinterpret_cast<const float4*>(src + (size_t)cl * HW_ + p4);
        *reinterpret_cast<float4*>(&tile[cl][p4]) = v;
    }
    __syncthreads();
    bf16* dst = curbf + ((size_t)b * HW_ + p0) * 256 + c0;
    #pragma unroll
    for (int it = 0; it < 4; it++) {
        int f = t + it * 256;
        int pl = f >> 4, c4 = (f & 15) * 4;
        ushort4 u;
        u.x = bfb(tile[c4 + 0][pl]); u.y = bfb(tile[c4 + 1][pl]);
        u.z = bfb(tile[c4 + 2][pl]); u.w = bfb(tile[c4 + 3][pl]);
        *reinterpret_cast<ushort4*>(dst + (size_t)pl * 256 + c4) = u;
    }
}

// ---------------------------------------------------------------- pool ----
__global__ __launch_bounds__(256)
void pool_kernel(const float* __restrict__ init_embed,
                 const float* __restrict__ init_seg,
                 bf16* __restrict__ fibf, float* __restrict__ si)
{
    int idx = blockIdx.x * 256 + threadIdx.x;
    int total = B_ * (C_ + 2) * KPP;
    if (idx >= total) return;
    int k  = idx % KPP;
    int ch = (idx / KPP) % (C_ + 2);
    int b  = idx / (KPP * (C_ + 2));
    float s = 0.f;
    if (k < KP_) {
        int ph = k / PW_, pw = k % PW_;
        const float* src = (ch < C_)
            ? (init_embed + (((size_t)b * C_ + ch) * H_ + ph * 4) * W_ + pw * 4)
            : (init_seg   + (((size_t)b * 2 + (ch - C_)) * H_ + ph * 4) * W_ + pw * 4);
        #pragma unroll
        for (int r = 0; r < 4; r++) {
            float4 v = *reinterpret_cast<const float4*>(src + r * W_);
            s += v.x + v.y + v.z + v.w;
        }
        s *= (1.f / 16.f);
    }
    if (ch < C_) fibf[((size_t)b * KPP + k) * C_ + ch] = __float2bfloat16(s);
    else         si[(size_t)b * 2 * KPP + (ch - C_) * KPP + k] = s;
}

// ---------------------------------------------------------------- gmap ----
__global__ __launch_bounds__(128)
void gmap_mfma(const bf16* __restrict__ curbf, const bf16* __restrict__ fibf,
               const float* __restrict__ si, float* __restrict__ gout)
{
    __shared__ float bred[2][2][64];
    int b = blockIdx.y;
    int p0 = blockIdx.x * 64;
    int t = threadIdx.x, lane = t & 63, wm = t >> 6;
    int l15 = lane & 15, lk = lane >> 4;
    const bf16* cb = curbf + (size_t)b * HW_ * 256;
    const bf16* fb = fibf + (size_t)b * KPP * 256;
    const float* sib = si + (size_t)b * 2 * KPP;
    size_t bo[4];
    #pragma unroll
    for (int nt = 0; nt < 4; nt++)
        bo[nt] = (size_t)(p0 + nt * 16 + l15) * 256 + lk * 8;
    float best[2][4];
    #pragma unroll
    for (int s = 0; s < 2; s++)
        #pragma unroll
        for (int nt = 0; nt < 4; nt++) best[s][nt] = -INFINITY;

    for (int ch = 0; ch < 5; ch++) {
        int kp0 = ch * 128;
        f32x4 acc[4][4] = {};
        for (int kc = 0; kc < 8; kc++) {
            short8 a[4], bbf[4];
            #pragma unroll
            for (int mt = 0; mt < 4; mt++)
                a[mt] = *reinterpret_cast<const short8*>(
                    fb + (size_t)(kp0 + wm * 64 + mt * 16 + l15) * 256 + kc * 32 + lk * 8);
            #pragma unroll
            for (int nt = 0; nt < 4; nt++)
                bbf[nt] = *reinterpret_cast<const short8*>(cb + bo[nt] + kc * 32);
            #pragma unroll
            for (int mt = 0; mt < 4; mt++)
                #pragma unroll
                for (int nt = 0; nt < 4; nt++)
                    acc[mt][nt] = __builtin_amdgcn_mfma_f32_16x16x32_bf16(
                        a[mt], bbf[nt], acc[mt][nt], 0, 0, 0);
        }
        #pragma unroll
        for (int mt = 0; mt < 4; mt++) {
            int rb = kp0 + wm * 64 + mt * 16 + lk * 4;
            float4 s0 = *reinterpret_cast<const float4*>(sib + rb);
            float4 s1 = *reinterpret_cast<const float4*>(sib + KPP + rb);
            const float* s0p = reinterpret_cast<const float*>(&s0);
            const float* s1p = reinterpret_cast<const float*>(&s1);
            #pragma unroll
            for (int nt = 0; nt < 4; nt++)
                #pragma unroll
                for (int r = 0; r < 4; r++) {
                    float v = acc[mt][nt][r];
                    best[0][nt] = fmaxf(best[0][nt], v * s0p[r]);
                    best[1][nt] = fmaxf(best[1][nt], v * s1p[r]);
                }
        }
    }
    #pragma unroll
    for (int s = 0; s < 2; s++)
        #pragma unroll
        for (int nt = 0; nt < 4; nt++) {
            float v = best[s][nt];
            v = fmaxf(v, __shfl_xor(v, 16));
            v = fmaxf(v, __shfl_xor(v, 32));
            if (lk == 0) bred[wm][s][nt * 16 + l15] = v;
        }
    __syncthreads();
    if (t < 128) {
        int s = t >> 6, pxl = t & 63;
        gout[((size_t)b * 2 + s) * HW_ + p0 + pxl] = fmaxf(bred[0][s][pxl], bred[1][s][pxl]);
    }
}

// ---------------------------------------------------------------- lmap ----
__global__ __launch_bounds__(256)
void lmap_mfma(const bf16* __restrict__ curbf, const bf16* __restrict__ prevbf,
               const float* __restrict__ prev_seg, float* __restrict__ lout, int b0)
{
    constexpr int GSTR = 257;
    constexpr int SEGB = 64 * GSTR;
    constexpr int REDB = SEGB + 512;
    __shared__ float gl[REDB + 256];
    int b = b0 + blockIdx.y;
    const bf16* pb = prevbf + (size_t)blockIdx.y * HW_ * 256;
    const bf16* cb = curbf + (size_t)b * HW_ * 256;
    int tile = blockIdx.x;
    int ty0 = (tile / 12) * 8, tx0 = (tile % 12) * 8;
    int t = threadIdx.x, lane = t & 63, wq = t >> 6;
    int l15 = lane & 15, lk = lane >> 4;

    size_t aoff[4];
    #pragma unroll
    for (int mt = 0; mt < 4; mt++) {
        int m = mt * 16 + l15;
        int gpx = (ty0 + (m >> 3)) * W_ + tx0 + (m & 7);
        aoff[mt] = (size_t)gpx * 256 + lk * 8;
    }
    bool pred[4];
    size_t boff[4];
    int gx = tx0 - 4 + l15;
    bool colok = (gx >= 0) && (gx < W_);
    #pragma unroll
    for (int nt = 0; nt < 4; nt++) {
        int gy = ty0 - 4 + wq * 4 + nt;
        pred[nt] = colok && (gy >= 0) && (gy < H_);
        boff[nt] = pred[nt] ? ((size_t)(gy * W_ + gx) * 256 + lk * 8) : 0;
    }

    f32x4 acc[4][4] = {};
    const short8 Z8 = {0, 0, 0, 0, 0, 0, 0, 0};
    for (int kc = 0; kc < 8; kc++) {
        short8 a[4], bb[4];
        #pragma unroll
        for (int mt = 0; mt < 4; mt++)
            a[mt] = *reinterpret_cast<const short8*>(cb + aoff[mt] + kc * 32);
        #pragma unroll
        for (int nt = 0; nt < 4; nt++) {
            short8 v = Z8;
            if (pred[nt]) v = *reinterpret_cast<const short8*>(pb + boff[nt] + kc * 32);
            bb[nt] = v;
        }
        #pragma unroll
        for (int mt = 0; mt < 4; mt++)
            #pragma unroll
            for (int nt = 0; nt < 4; nt++)
                acc[mt][nt] = __builtin_amdgcn_mfma_f32_16x16x32_bf16(
                    a[mt], bb[nt], acc[mt][nt], 0, 0, 0);
    }
    #pragma unroll
    for (int mt = 0; mt < 4; mt++)
        #pragma unroll
        for (int nt = 0; nt < 4; nt++)
            #pragma unroll
            for (int r = 0; r < 4; r++)
                gl[(mt * 16 + lk * 4 + r) * GSTR + wq * 64 + nt * 16 + l15] = acc[mt][nt][r];
    #pragma unroll
    for (int it = 0; it < 2; it++) {
        int f = t + it * 256;
        int s = f >> 8, wp = f & 255;
        int wy = wp >> 4, wx = wp & 15;
        int gy = ty0 - 4 + wy, gxx = tx0 - 4 + wx;
        float v = 0.f;
        if (gy >= 0 && gy < H_ && gxx >= 0 && gxx < W_)
            v = prev_seg[((size_t)b * 2 + s) * HW_ + gy * W_ + gxx] * (1.f / 256.f);
        gl[SEGB + f] = v;
    }
    __syncthreads();
    {
        int m = t & 63;
        int sh = t >> 6;
        int s = sh >> 1, hh = sh & 1;
        int py = m >> 3, lx = m & 7;
        const float* gr = gl + m * GSTR;
        const float* sr = gl + SEGB + s * 256;
        float mx = -INFINITY;
        int wr0 = hh * 5, wr1 = hh ? 9 : 5;
        for (int wr = wr0; wr < wr1; ++wr) {
            int base = (py + wr) * 16 + lx;
            #pragma unroll
            for (int wc = 0; wc < 9; ++wc)
                mx = fmaxf(mx, gr[base + wc] * sr[base + wc]);
        }
        gl[REDB + sh * 64 + m] = mx;
    }
    __syncthreads();
    if (t < 128) {
        int s = t >> 6, m = t & 63;
        float v = fmaxf(gl[REDB + (s * 2 + 0) * 64 + m], gl[REDB + (s * 2 + 1) * 64 + m]);
        int gpx = (ty0 + (m >> 3)) * W_ + tx0 + (m & 7);
        lout[((size_t)b * 2 + s) * HW_ + gpx] = v;
    }
}

// ---------------------------------------------------------------- packs ----
__global__ __launch_bounds__(256)
void pack_dec_kernel(const float* __restrict__ dec, bf16* __restrict__ hcat)
{
    __shared__ float tile[64][68];
    int b = blockIdx.z, c0 = blockIdx.y * 64, p0 = blockIdx.x * 64;
    int t = threadIdx.x;
    const float* src = dec + ((size_t)b * C_ + c0) * HW_ + p0;
    #pragma unroll
    for (int it = 0; it < 4; it++) {
        int f = t + it * 256;
        int cl = f >> 4, p4 = (f & 15) * 4;
        float4 v = *reinterpret_cast<const float4*>(src + (size_t)cl * HW_ + p4);
        *reinterpret_cast<float4*>(&tile[cl][p4]) = v;
    }
    __syncthreads();
    #pragma unroll
    for (int it = 0; it < 4; it++) {
        int f = t + it * 256;
        int pl = f >> 4, c4 = (f & 15) * 4;
        int p = p0 + pl;
        int y = p / 96, x = p % 96;
        int pos = (y + 1) * HP_ + x + 1;
        ushort4 u;
        u.x = bfb(tile[c4 + 0][pl]); u.y = bfb(tile[c4 + 1][pl]);
        u.z = bfb(tile[c4 + 2][pl]); u.w = bfb(tile[c4 + 3][pl]);
        *reinterpret_cast<ushort4*>(hcat + ((size_t)b * HPW + pos) * CH_ + c0 + c4) = u;
    }
}

__global__ __launch_bounds__(256)
void pack_small_kernel(const float* __restrict__ gout,
                       const float* __restrict__ lout,
                       const float* __restrict__ init_seg,
                       const float* __restrict__ prev_seg,
                       bf16* __restrict__ hcat)
{
    int idx = blockIdx.x * 256 + threadIdx.x;
    if (idx >= B_ * HW_) return;
    int b = idx / HW_, p = idx % HW_;
    int y = p / 96, x = p % 96;
    int pos = (y + 1) * HP_ + x + 1;
    bf16* dst = hcat + ((size_t)b * HPW + pos) * CH_;
    float g0 = gout[((size_t)b * 2 + 0) * HW_ + p];
    float g1 = gout[((size_t)b * 2 + 1) * HW_ + p];
    float i0 = init_seg[((size_t)b * 2 + 0) * HW_ + p];
    float i1 = init_seg[((size_t)b * 2 + 1) * HW_ + p];
    float l0 = lout[((size_t)b * 2 + 0) * HW_ + p];
    float l1 = lout[((size_t)b * 2 + 1) * HW_ + p];
    float q0 = prev_seg[((size_t)b * 2 + 0) * HW_ + p];
    float q1 = prev_seg[((size_t)b * 2 + 1) * HW_ + p];
    ushort4 u; u.x = bfb(g0); u.y = bfb(g1); u.z = bfb(i0); u.w = bfb(i1);
    *reinterpret_cast<ushort4*>(dst + 256) = u;
    ushort4 u2; u2.x = bfb(l0); u2.y = bfb(l1); u2.z = bfb(q0); u2.w = bfb(q1);
    *reinterpret_cast<ushort4*>(dst + 260) = u2;
}

// ---------------------------------------------------------------- conv1 ----
// LDS-staged double-buffered implicit GEMM. Block: 256 thr (4 waves), tile
// 128 oc x (8 rows x 16 cols). Wave (wm = oc half, wp = px half of 4 rows).
// Per 32-ch chunk: stage [10][18][40pad] window; 9 taps x 16 MFMA per wave.
__global__ __launch_bounds__(256)
void conv1_mfma(const bf16* __restrict__ hcat, const bf16* __restrict__ w1bf,
                const float* __restrict__ b1, bf16* __restrict__ hmid)
{
    __shared__ bf16 bs[2][7200];            // [10][18][40]
    int b = blockIdx.y;
    int tile = blockIdx.x;                  // 12 row-tiles x 6 col-tiles
    int ty = (tile / 6) * 8, tx = (tile % 6) * 16;
    int t = threadIdx.x, lane = t & 63;
    int wid = t >> 6, wm = wid & 1, wp = wid >> 1;
    int l15 = lane & 15, lk = lane >> 4;
    const bf16* hb = hcat + (size_t)b * HPW * CH_;

    // staging chunk addresses (f = t, t+256, t+512 ; f<720 ; px=f>>2, lk8=f&3)
    int px0 = t >> 2,            c80 = (t & 3) * 8;
    int px1 = (t + 256) >> 2,    c81 = c80;          // (f&3) identical for +256
    int px2 = (t + 512) >> 2,    c82 = c80;
    bool ok2 = (t + 512) < 720;
    size_t g0 = ((size_t)((ty + px0 / 18) * HP_ + tx + px0 % 18)) * CH_ + c80;
    size_t g1 = ((size_t)((ty + px1 / 18) * HP_ + tx + px1 % 18)) * CH_ + c81;
    size_t g2 = ok2 ? (((size_t)((ty + px2 / 18) * HP_ + tx + px2 % 18)) * CH_ + c82) : 0;
    int s0 = px0 * 40 + c80, s1 = px1 * 40 + c81, s2 = px2 * 40 + c82;

    int aocb = (wm * 64 + l15) * 32 + lk * 8;
    f32x4 acc[4][4] = {};
    const short8 Z8 = {0, 0, 0, 0, 0, 0, 0, 0};

    // prologue: stage icc=0
    short8 r0 = *reinterpret_cast<const short8*>(hb + g0);
    short8 r1 = *reinterpret_cast<const short8*>(hb + g1);
    short8 r2 = ok2 ? *reinterpret_cast<const short8*>(hb + g2) : Z8;
    *reinterpret_cast<short8*>(&bs[0][s0]) = r0;
    *reinterpret_cast<short8*>(&bs[0][s1]) = r1;
    if (ok2) *reinterpret_cast<short8*>(&bs[0][s2]) = r2;
    __syncthreads();

    for (int icc = 0; icc < 9; icc++) {
        if (icc < 8) {                       // issue next chunk's global loads
            size_t o = (size_t)(icc + 1) * 32;
            r0 = *reinterpret_cast<const short8*>(hb + g0 + o);
            r1 = *reinterpret_cast<const short8*>(hb + g1 + o);
            if (ok2) r2 = *reinterpret_cast<const short8*>(hb + g2 + o);
        }
        const bf16* bcur = bs[icc & 1];
        const bf16* wbase = w1bf + (size_t)icc * 4096;
        #pragma unroll
        for (int tap = 0; tap < 9; tap++) {
            int ky = tap / 3, kx = tap % 3;
            const bf16* wt = wbase + (size_t)tap * 9 * 4096;
            short8 a[4], bb[4];
            #pragma unroll
            for (int mt = 0; mt < 4; mt++)
                a[mt] = *reinterpret_cast<const short8*>(wt + aocb + mt * 512);
            #pragma unroll
            for (int nt = 0; nt < 4; nt++)
                bb[nt] = *reinterpret_cast<const short8*>(
                    &bcur[((wp * 4 + nt + ky) * 18 + l15 + kx) * 40 + lk * 8]);
            #pragma unroll
            for (int mt = 0; mt < 4; mt++)
                #pragma unroll
                for (int nt = 0; nt < 4; nt++)
                    acc[mt][nt] = __builtin_amdgcn_mfma_f32_16x16x32_bf16(
                        a[mt], bb[nt], acc[mt][nt], 0, 0, 0);
        }
        if (icc < 8) {
            bf16* bnxt = bs[(icc + 1) & 1];
            *reinterpret_cast<short8*>(&bnxt[s0]) = r0;
            *reinterpret_cast<short8*>(&bnxt[s1]) = r1;
            if (ok2) *reinterpret_cast<short8*>(&bnxt[s2]) = r2;
            __syncthreads();
        }
    }

    bf16* hm = hmid + (size_t)b * C1O * HW_;
    #pragma unroll
    for (int mt = 0; mt < 4; mt++) {
        int ocb = wm * 64 + mt * 16 + lk * 4;
        float4 bias = *reinterpret_cast<const float4*>(b1 + ocb);
        const float* bp = reinterpret_cast<const float*>(&bias);
        #pragma unroll
        for (int nt = 0; nt < 4; nt++) {
            int y = ty + wp * 4 + nt, x = tx + l15;
            #pragma unroll
            for (int r = 0; r < 4; r++) {
                float v = fmaxf(acc[mt][nt][r] + bp[r], 0.f);
                hm[(size_t)(ocb + r) * HW_ + y * W_ + x] = __float2bfloat16(v);
            }
        }
    }
}

// ---------------------------------------------------------------- conv2 ----
__global__ __launch_bounds__(256)
void conv2_kernel(const bf16* __restrict__ hmid,
                  const float* __restrict__ W2,
                  const float* __restrict__ b2,
                  float* __restrict__ out)
{
    __shared__ float in_s[16][18 * 19];
    __shared__ float w2_s[2][128 * 9];
    int b = blockIdx.y;
    int tile = blockIdx.x;
    int y0 = (tile / 6) * 16, x0 = (tile % 6) * 16;
    int t = threadIdx.x;
    int r = t >> 4, c = t & 15;
    for (int f = t; f < 2 * 128 * 9; f += 256) w2_s[f / 1152][f % 1152] = W2[f];
    float acc0 = 0.f, acc1 = 0.f;
    const bf16* hb = hmid + (size_t)b * C1O * HW_;
    for (int ic0 = 0; ic0 < 128; ic0 += 16) {
        __syncthreads();
        for (int f = t; f < 16 * 18 * 18; f += 256) {
            int ic = f / 324; int rem = f % 324; int row = rem / 18, col = rem % 18;
            int gy = y0 - 1 + row, gxx = x0 - 1 + col;
            float v = 0.f;
            if (gy >= 0 && gy < H_ && gxx >= 0 && gxx < W_)
                v = __bfloat162float(hb[(size_t)(ic0 + ic) * HW_ + gy * W_ + gxx]);
            in_s[ic][row * 19 + col] = v;
        }
        __syncthreads();
        for (int ic = 0; ic < 16; ic++) {
            #pragma unroll
            for (int ky = 0; ky < 3; ky++) {
                #pragma unroll
                for (int kx = 0; kx < 3; kx++) {
                    float x = in_s[ic][(r + ky) * 19 + c + kx];
                    int wk = (ic0 + ic) * 9 + ky * 3 + kx;
                    acc0 += x * w2_s[0][wk];
                    acc1 += x * w2_s[1][wk];
                }
            }
        }
    }
    int py = (y0 + r) * W_ + x0 + c;
    out[((size_t)b * 2 + 0) * HW_ + py] = acc0 + b2[0];
    out[((size_t)b * 2 + 1) * HW_ + py] = acc1 + b2[1];
}

// ---------------------------------------------------------------- launch ----
extern "C" void kernel_launch(void* const* d_in, const int* in_sizes, int n_in,
                              void* d_out, int out_size, void* d_ws, size_t ws_size,
                              hipStream_t stream)
{
    const float* cur_embed  = (const float*)d_in[0];
    const float* cur_decode = (const float*)d_in[1];
    const float* init_embed = (const float*)d_in[2];
    const float* init_seg   = (const float*)d_in[3];
    const float* prev_embed = (const float*)d_in[4];
    const float* prev_seg   = (const float*)d_in[5];
    const float* W1 = (const float*)d_in[6];
    const float* b1 = (const float*)d_in[7];
    const float* W2 = (const float*)d_in[8];
    const float* b2 = (const float*)d_in[9];
    float* out = (float*)d_out;

    char* ws = (char*)d_ws;
    bf16* hcat  = (bf16*)ws;
    bf16* curbf = (bf16*)ws;                          // alias (dead before memset)
    const size_t HCAT_REGION = 41799680;
    bf16* hmid   = (bf16*)(ws + HCAT_REGION);
    bf16* fibf   = (bf16*)(ws + HCAT_REGION);         // phase-1 alias
    bf16* prevbf = (bf16*)(ws + HCAT_REGION);         // phase-2 alias (4 batches = 18,874,368 B)
    float* si  = (float*)(ws + HCAT_REGION + 2621440);
    bf16* w1bf = (bf16*)(ws + 60674048);
    float* gout = (float*)(ws + 61337600);
    float* lout = (float*)(ws + 61927424);

    { int total = 81 * 128 * 32;
      w1cvt_kernel<<<(total + 255) / 256, 256, 0, stream>>>(W1, w1bf); }
    { dim3 g(144, 4, B_);
      tcur_kernel<<<g, 256, 0, stream>>>(cur_embed, curbf); }
    { int total = B_ * (C_ + 2) * KPP;
      pool_kernel<<<(total + 255) / 256, 256, 0, stream>>>(init_embed, init_seg, fibf, si); }
    { dim3 g(144, B_);
      gmap_mfma<<<g, 128, 0, stream>>>(curbf, fibf, si, gout); }
    // lmap in 2 groups of 4 batches (prevbf aliases the dead fibf/hmid region)
    for (int g = 0; g < 2; g++) {
        dim3 gt(144, 4, 4);
        tcur_kernel<<<gt, 256, 0, stream>>>(prev_embed + (size_t)g * 4 * C_ * HW_, prevbf);
        dim3 gl(144, 4);
        lmap_mfma<<<gl, 256, 0, stream>>>(curbf, prevbf, prev_seg, lout, g * 4);
    }
    hipMemsetAsync(ws, 0, HCAT_REGION, stream);       // zero hcat; curbf dead
    { dim3 g(144, 4, B_);
      pack_dec_kernel<<<g, 256, 0, stream>>>(cur_decode, hcat); }
    { int total = B_ * HW_;
      pack_small_kernel<<<(total + 255) / 256, 256, 0, stream>>>(gout, lout, init_seg, prev_seg, hcat); }
    { dim3 g(72, B_);
      conv1_mfma<<<g, 256, 0, stream>>>(hcat, w1bf, b1, hmid); }
    { dim3 g(36, B_);
      conv2_kernel<<<g, 256, 0, stream>>>(hmid, W2, b2, out); }
}

// Round 5
// 479.610 us; speedup vs baseline: 4.6163x; 1.0123x over previous
//
#include <hip/hip_runtime.h>
#include <hip/hip_bf16.h>

// Round 5: conv1 -> no-LDS implicit GEMM with chunked-NHWC hcat (dense wave loads)
//          + depth-2 register pipeline (3 rotating frag buffers).
// ws layout (61.28 MB, aliased):
//   [0, 39,337,984)           hcat8 bf16 [8][8][9604][32]   -- ALSO curbf bf16 [8][9216][256] (dead at memset)
//   [39,337,984, 40,567,296)  hcat1 bf16 [8][9604][8] (tail ch 256..263)
//   [40,567,296, 59,441,664)  hmid bf16 [8][128][9216]
//       -- phase1 alias: fibf bf16 [8][640][256] @ +0, si f32 [8][2][640] @ +2,621,440
//       -- phase2 alias: prevbf bf16 [4][9216][256] (exactly 18,874,368 B)
//   [59,441,664, 60,105,216)  W1bf bf16 [81][128][32]
//   [60,105,216, 60,695,040)  gout f32 [8][2][9216]
//   [60,695,040, 61,284,864)  lout f32 [8][2][9216]

typedef __hip_bfloat16 bf16;
typedef __attribute__((ext_vector_type(8))) short short8;
typedef __attribute__((ext_vector_type(4))) float f32x4;

constexpr int B_  = 8;
constexpr int C_  = 256;
constexpr int H_  = 96;
constexpr int W_  = 96;
constexpr int HW_ = H_ * W_;       // 9216
constexpr int PW_ = 24;
constexpr int KP_ = 576;
constexpr int KPP = 640;
constexpr int HP_ = 98;
constexpr int HPW = HP_ * HP_;     // 9604
constexpr int C1O = 128;
constexpr int CHK = HPW * 32;      // 307,328 elems per 32-ch chunk

__device__ __forceinline__ unsigned short bfb(float f) {
    bf16 h = __float2bfloat16(f);
    return *reinterpret_cast<unsigned short*>(&h);
}

// ------------------------------------------------------------ W1 convert ----
__global__ __launch_bounds__(256)
void w1cvt_kernel(const float* __restrict__ W1, bf16* __restrict__ w1bf)
{
    int idx = blockIdx.x * 256 + threadIdx.x;
    if (idx >= 81 * 128 * 32) return;
    int ic = idx & 31;
    int oc = (idx >> 5) & 127;
    int ks = idx >> 12;
    int tap = ks / 9, icc = ks % 9;
    int icg = icc * 32 + ic;
    float v = (icg < 264) ? W1[((size_t)oc * 264 + icg) * 9 + tap] : 0.f;
    w1bf[idx] = __float2bfloat16(v);
}

// ------------------------------------------------------- NCHW->NHWC bf16 ----
__global__ __launch_bounds__(256)
void tcur_kernel(const float* __restrict__ cur, bf16* __restrict__ curbf)
{
    __shared__ float tile[64][68];
    int b = blockIdx.z, c0 = blockIdx.y * 64, p0 = blockIdx.x * 64;
    int t = threadIdx.x;
    const float* src = cur + ((size_t)b * C_ + c0) * HW_ + p0;
    #pragma unroll
    for (int it = 0; it < 4; it++) {
        int f = t + it * 256;
        int cl = f >> 4, p4 = (f & 15) * 4;
        float4 v = *reinterpret_cast<const float4*>(src + (size_t)cl * HW_ + p4);
        *reinterpret_cast<float4*>(&tile[cl][p4]) = v;
    }
    __syncthreads();
    bf16* dst = curbf + ((size_t)b * HW_ + p0) * 256 + c0;
    #pragma unroll
    for (int it = 0; it < 4; it++) {
        int f = t + it * 256;
        int pl = f >> 4, c4 = (f & 15) * 4;
        ushort4 u;
        u.x = bfb(tile[c4 + 0][pl]); u.y = bfb(tile[c4 + 1][pl]);
        u.z = bfb(tile[c4 + 2][pl]); u.w = bfb(tile[c4 + 3][pl]);
        *reinterpret_cast<ushort4*>(dst + (size_t)pl * 256 + c4) = u;
    }
}

// ---------------------------------------------------------------- pool ----
__global__ __launch_bounds__(256)
void pool_kernel(const float* __restrict__ init_embed,
                 const float* __restrict__ init_seg,
                 bf16* __restrict__ fibf, float* __restrict__ si)
{
    int idx = blockIdx.x * 256 + threadIdx.x;
    int total = B_ * (C_ + 2) * KPP;
    if (idx >= total) return;
    int k  = idx % KPP;
    int ch = (idx / KPP) % (C_ + 2);
    int b  = idx / (KPP * (C_ + 2));
    float s = 0.f;
    if (k < KP_) {
        int ph = k / PW_, pw = k % PW_;
        const float* src = (ch < C_)
            ? (init_embed + (((size_t)b * C_ + ch) * H_ + ph * 4) * W_ + pw * 4)
            : (init_seg   + (((size_t)b * 2 + (ch - C_)) * H_ + ph * 4) * W_ + pw * 4);
        #pragma unroll
        for (int r = 0; r < 4; r++) {
            float4 v = *reinterpret_cast<const float4*>(src + r * W_);
            s += v.x + v.y + v.z + v.w;
        }
        s *= (1.f / 16.f);
    }
    if (ch < C_) fibf[((size_t)b * KPP + k) * C_ + ch] = __float2bfloat16(s);
    else         si[(size_t)b * 2 * KPP + (ch - C_) * KPP + k] = s;
}

// ---------------------------------------------------------------- gmap ----
__global__ __launch_bounds__(128)
void gmap_mfma(const bf16* __restrict__ curbf, const bf16* __restrict__ fibf,
               const float* __restrict__ si, float* __restrict__ gout)
{
    __shared__ float bred[2][2][64];
    int b = blockIdx.y;
    int p0 = blockIdx.x * 64;
    int t = threadIdx.x, lane = t & 63, wm = t >> 6;
    int l15 = lane & 15, lk = lane >> 4;
    const bf16* cb = curbf + (size_t)b * HW_ * 256;
    const bf16* fb = fibf + (size_t)b * KPP * 256;
    const float* sib = si + (size_t)b * 2 * KPP;
    size_t bo[4];
    #pragma unroll
    for (int nt = 0; nt < 4; nt++)
        bo[nt] = (size_t)(p0 + nt * 16 + l15) * 256 + lk * 8;
    float best[2][4];
    #pragma unroll
    for (int s = 0; s < 2; s++)
        #pragma unroll
        for (int nt = 0; nt < 4; nt++) best[s][nt] = -INFINITY;

    for (int ch = 0; ch < 5; ch++) {
        int kp0 = ch * 128;
        f32x4 acc[4][4] = {};
        for (int kc = 0; kc < 8; kc++) {
            short8 a[4], bbf[4];
            #pragma unroll
            for (int mt = 0; mt < 4; mt++)
                a[mt] = *reinterpret_cast<const short8*>(
                    fb + (size_t)(kp0 + wm * 64 + mt * 16 + l15) * 256 + kc * 32 + lk * 8);
            #pragma unroll
            for (int nt = 0; nt < 4; nt++)
                bbf[nt] = *reinterpret_cast<const short8*>(cb + bo[nt] + kc * 32);
            #pragma unroll
            for (int mt = 0; mt < 4; mt++)
                #pragma unroll
                for (int nt = 0; nt < 4; nt++)
                    acc[mt][nt] = __builtin_amdgcn_mfma_f32_16x16x32_bf16(
                        a[mt], bbf[nt], acc[mt][nt], 0, 0, 0);
        }
        #pragma unroll
        for (int mt = 0; mt < 4; mt++) {
            int rb = kp0 + wm * 64 + mt * 16 + lk * 4;
            float4 s0 = *reinterpret_cast<const float4*>(sib + rb);
            float4 s1 = *reinterpret_cast<const float4*>(sib + KPP + rb);
            const float* s0p = reinterpret_cast<const float*>(&s0);
            const float* s1p = reinterpret_cast<const float*>(&s1);
            #pragma unroll
            for (int nt = 0; nt < 4; nt++)
                #pragma unroll
                for (int r = 0; r < 4; r++) {
                    float v = acc[mt][nt][r];
                    best[0][nt] = fmaxf(best[0][nt], v * s0p[r]);
                    best[1][nt] = fmaxf(best[1][nt], v * s1p[r]);
                }
        }
    }
    #pragma unroll
    for (int s = 0; s < 2; s++)
        #pragma unroll
        for (int nt = 0; nt < 4; nt++) {
            float v = best[s][nt];
            v = fmaxf(v, __shfl_xor(v, 16));
            v = fmaxf(v, __shfl_xor(v, 32));
            if (lk == 0) bred[wm][s][nt * 16 + l15] = v;
        }
    __syncthreads();
    if (t < 128) {
        int s = t >> 6, pxl = t & 63;
        gout[((size_t)b * 2 + s) * HW_ + p0 + pxl] = fmaxf(bred[0][s][pxl], bred[1][s][pxl]);
    }
}

// ---------------------------------------------------------------- lmap ----
__global__ __launch_bounds__(256)
void lmap_mfma(const bf16* __restrict__ curbf, const bf16* __restrict__ prevbf,
               const float* __restrict__ prev_seg, float* __restrict__ lout, int b0)
{
    constexpr int GSTR = 257;
    constexpr int SEGB = 64 * GSTR;
    constexpr int REDB = SEGB + 512;
    __shared__ float gl[REDB + 256];
    int b = b0 + blockIdx.y;
    const bf16* pb = prevbf + (size_t)blockIdx.y * HW_ * 256;
    const bf16* cb = curbf + (size_t)b * HW_ * 256;
    int tile = blockIdx.x;
    int ty0 = (tile / 12) * 8, tx0 = (tile % 12) * 8;
    int t = threadIdx.x, lane = t & 63, wq = t >> 6;
    int l15 = lane & 15, lk = lane >> 4;

    size_t aoff[4];
    #pragma unroll
    for (int mt = 0; mt < 4; mt++) {
        int m = mt * 16 + l15;
        int gpx = (ty0 + (m >> 3)) * W_ + tx0 + (m & 7);
        aoff[mt] = (size_t)gpx * 256 + lk * 8;
    }
    bool pred[4];
    size_t boff[4];
    int gx = tx0 - 4 + l15;
    bool colok = (gx >= 0) && (gx < W_);
    #pragma unroll
    for (int nt = 0; nt < 4; nt++) {
        int gy = ty0 - 4 + wq * 4 + nt;
        pred[nt] = colok && (gy >= 0) && (gy < H_);
        boff[nt] = pred[nt] ? ((size_t)(gy * W_ + gx) * 256 + lk * 8) : 0;
    }

    f32x4 acc[4][4] = {};
    const short8 Z8 = {0, 0, 0, 0, 0, 0, 0, 0};
    for (int kc = 0; kc < 8; kc++) {
        short8 a[4], bb[4];
        #pragma unroll
        for (int mt = 0; mt < 4; mt++)
            a[mt] = *reinterpret_cast<const short8*>(cb + aoff[mt] + kc * 32);
        #pragma unroll
        for (int nt = 0; nt < 4; nt++) {
            short8 v = Z8;
            if (pred[nt]) v = *reinterpret_cast<const short8*>(pb + boff[nt] + kc * 32);
            bb[nt] = v;
        }
        #pragma unroll
        for (int mt = 0; mt < 4; mt++)
            #pragma unroll
            for (int nt = 0; nt < 4; nt++)
                acc[mt][nt] = __builtin_amdgcn_mfma_f32_16x16x32_bf16(
                    a[mt], bb[nt], acc[mt][nt], 0, 0, 0);
    }
    #pragma unroll
    for (int mt = 0; mt < 4; mt++)
        #pragma unroll
        for (int nt = 0; nt < 4; nt++)
            #pragma unroll
            for (int r = 0; r < 4; r++)
                gl[(mt * 16 + lk * 4 + r) * GSTR + wq * 64 + nt * 16 + l15] = acc[mt][nt][r];
    #pragma unroll
    for (int it = 0; it < 2; it++) {
        int f = t + it * 256;
        int s = f >> 8, wp = f & 255;
        int wy = wp >> 4, wx = wp & 15;
        int gy = ty0 - 4 + wy, gxx = tx0 - 4 + wx;
        float v = 0.f;
        if (gy >= 0 && gy < H_ && gxx >= 0 && gxx < W_)
            v = prev_seg[((size_t)b * 2 + s) * HW_ + gy * W_ + gxx] * (1.f / 256.f);
        gl[SEGB + f] = v;
    }
    __syncthreads();
    {
        int m = t & 63;
        int sh = t >> 6;
        int s = sh >> 1, hh = sh & 1;
        int py = m >> 3, lx = m & 7;
        const float* gr = gl + m * GSTR;
        const float* sr = gl + SEGB + s * 256;
        float mx = -INFINITY;
        int wr0 = hh * 5, wr1 = hh ? 9 : 5;
        for (int wr = wr0; wr < wr1; ++wr) {
            int base = (py + wr) * 16 + lx;
            #pragma unroll
            for (int wc = 0; wc < 9; ++wc)
                mx = fmaxf(mx, gr[base + wc] * sr[base + wc]);
        }
        gl[REDB + sh * 64 + m] = mx;
    }
    __syncthreads();
    if (t < 128) {
        int s = t >> 6, m = t & 63;
        float v = fmaxf(gl[REDB + (s * 2 + 0) * 64 + m], gl[REDB + (s * 2 + 1) * 64 + m]);
        int gpx = (ty0 + (m >> 3)) * W_ + tx0 + (m & 7);
        lout[((size_t)b * 2 + s) * HW_ + gpx] = v;
    }
}

// ---------------------------------------------------------------- packs ----
// cur_decode NCHW f32 -> chunked NHWC bf16 (chunks 0..7)
__global__ __launch_bounds__(256)
void pack_dec_kernel(const float* __restrict__ dec, bf16* __restrict__ hcat8)
{
    __shared__ float tile[64][68];
    int b = blockIdx.z, c0 = blockIdx.y * 64, p0 = blockIdx.x * 64;
    int t = threadIdx.x;
    const float* src = dec + ((size_t)b * C_ + c0) * HW_ + p0;
    #pragma unroll
    for (int it = 0; it < 4; it++) {
        int f = t + it * 256;
        int cl = f >> 4, p4 = (f & 15) * 4;
        float4 v = *reinterpret_cast<const float4*>(src + (size_t)cl * HW_ + p4);
        *reinterpret_cast<float4*>(&tile[cl][p4]) = v;
    }
    __syncthreads();
    #pragma unroll
    for (int it = 0; it < 4; it++) {
        int f = t + it * 256;
        int pl = f >> 4, c4 = (f & 15) * 4;
        int p = p0 + pl;
        int y = p / 96, x = p % 96;
        int pos = (y + 1) * HP_ + x + 1;
        int ch = c0 + c4;
        ushort4 u;
        u.x = bfb(tile[c4 + 0][pl]); u.y = bfb(tile[c4 + 1][pl]);
        u.z = bfb(tile[c4 + 2][pl]); u.w = bfb(tile[c4 + 3][pl]);
        bf16* dst = hcat8 + ((size_t)b * 8 + (ch >> 5)) * CHK + (size_t)pos * 32 + (ch & 31);
        *reinterpret_cast<ushort4*>(dst) = u;
    }
}

// gmap(0,1) init_seg(2,3) lmap(4,5) prev_seg(6,7) -> tail chunk [pos][8]
__global__ __launch_bounds__(256)
void pack_small_kernel(const float* __restrict__ gout,
                       const float* __restrict__ lout,
                       const float* __restrict__ init_seg,
                       const float* __restrict__ prev_seg,
                       bf16* __restrict__ hcat1)
{
    int idx = blockIdx.x * 256 + threadIdx.x;
    if (idx >= B_ * HW_) return;
    int b = idx / HW_, p = idx % HW_;
    int y = p / 96, x = p % 96;
    int pos = (y + 1) * HP_ + x + 1;
    bf16* dst = hcat1 + ((size_t)b * HPW + pos) * 8;
    float g0 = gout[((size_t)b * 2 + 0) * HW_ + p];
    float g1 = gout[((size_t)b * 2 + 1) * HW_ + p];
    float i0 = init_seg[((size_t)b * 2 + 0) * HW_ + p];
    float i1 = init_seg[((size_t)b * 2 + 1) * HW_ + p];
    float l0 = lout[((size_t)b * 2 + 0) * HW_ + p];
    float l1 = lout[((size_t)b * 2 + 1) * HW_ + p];
    float q0 = prev_seg[((size_t)b * 2 + 0) * HW_ + p];
    float q1 = prev_seg[((size_t)b * 2 + 1) * HW_ + p];
    ushort4 u; u.x = bfb(g0); u.y = bfb(g1); u.z = bfb(i0); u.w = bfb(i1);
    *reinterpret_cast<ushort4*>(dst) = u;
    ushort4 u2; u2.x = bfb(l0); u2.y = bfb(l1); u2.z = bfb(q0); u2.w = bfb(q1);
    *reinterpret_cast<ushort4*>(dst + 4) = u2;
}

// ---------------------------------------------------------------- conv1 ----
// No-LDS implicit GEMM over chunked NHWC. 2 waves: wave = 64oc x 64px.
// Depth-2 register pipeline over the 81 K-steps (tap*9+icc), fully unrolled.
__global__ __launch_bounds__(128)
void conv1_mfma(const bf16* __restrict__ hcat8, const bf16* __restrict__ hcat1,
                const bf16* __restrict__ w1bf, const float* __restrict__ b1,
                bf16* __restrict__ hmid)
{
    int b = blockIdx.y;
    int p0 = blockIdx.x * 64;
    int t = threadIdx.x, lane = t & 63, wm = t >> 6;
    int l15 = lane & 15, lk = lane >> 4;
    const bf16* hb8 = hcat8 + (size_t)b * 8 * CHK;
    const bf16* hb1 = hcat1 + (size_t)b * HPW * 8;
    int pos[4];
    #pragma unroll
    for (int nt = 0; nt < 4; nt++) {
        int p = p0 + nt * 16 + l15;
        pos[nt] = (p / 96) * HP_ + (p % 96);
    }
    int aocb = (wm * 64 + l15) * 32 + lk * 8;
    f32x4 acc[4][4] = {};
    short8 abuf[3][4], bbuf[3][4];
    const short8 Z8 = {0, 0, 0, 0, 0, 0, 0, 0};

    auto LOAD = [&](int s, int ph) {
        int tap = s / 9, icc = s % 9;
        int toff = (tap / 3) * HP_ + (tap % 3);
        const bf16* wp = w1bf + (size_t)s * 4096;
        #pragma unroll
        for (int mt = 0; mt < 4; mt++)
            abuf[ph][mt] = *reinterpret_cast<const short8*>(wp + aocb + mt * 512);
        if (icc < 8) {
            const bf16* cp = hb8 + (size_t)icc * CHK;
            #pragma unroll
            for (int nt = 0; nt < 4; nt++)
                bbuf[ph][nt] = *reinterpret_cast<const short8*>(
                    cp + (size_t)(pos[nt] + toff) * 32 + lk * 8);
        } else {
            #pragma unroll
            for (int nt = 0; nt < 4; nt++) {
                short8 v = *reinterpret_cast<const short8*>(
                    hb1 + (size_t)(pos[nt] + toff) * 8);
                bbuf[ph][nt] = (lk == 0) ? v : Z8;
            }
        }
    };

    LOAD(0, 0);
    LOAD(1, 1);
    #pragma unroll
    for (int s = 0; s < 81; ++s) {
        int ph = s % 3;
        if (s + 2 < 81) LOAD(s + 2, (s + 2) % 3);
        #pragma unroll
        for (int mt = 0; mt < 4; mt++)
            #pragma unroll
            for (int nt = 0; nt < 4; nt++)
                acc[mt][nt] = __builtin_amdgcn_mfma_f32_16x16x32_bf16(
                    abuf[ph][mt], bbuf[ph][nt], acc[mt][nt], 0, 0, 0);
    }

    bf16* hm = hmid + (size_t)b * C1O * HW_;
    #pragma unroll
    for (int mt = 0; mt < 4; mt++) {
        int ocb = wm * 64 + mt * 16 + lk * 4;
        float4 bias = *reinterpret_cast<const float4*>(b1 + ocb);
        const float* bp = reinterpret_cast<const float*>(&bias);
        #pragma unroll
        for (int nt = 0; nt < 4; nt++) {
            int p = p0 + nt * 16 + l15;
            #pragma unroll
            for (int r = 0; r < 4; r++) {
                float v = fmaxf(acc[mt][nt][r] + bp[r], 0.f);
                hm[(size_t)(ocb + r) * HW_ + p] = __float2bfloat16(v);
            }
        }
    }
}

// ---------------------------------------------------------------- conv2 ----
__global__ __launch_bounds__(256)
void conv2_kernel(const bf16* __restrict__ hmid,
                  const float* __restrict__ W2,
                  const float* __restrict__ b2,
                  float* __restrict__ out)
{
    __shared__ float in_s[16][18 * 19];
    __shared__ float w2_s[2][128 * 9];
    int b = blockIdx.y;
    int tile = blockIdx.x;
    int y0 = (tile / 6) * 16, x0 = (tile % 6) * 16;
    int t = threadIdx.x;
    int r = t >> 4, c = t & 15;
    for (int f = t; f < 2 * 128 * 9; f += 256) w2_s[f / 1152][f % 1152] = W2[f];
    float acc0 = 0.f, acc1 = 0.f;
    const bf16* hb = hmid + (size_t)b * C1O * HW_;
    for (int ic0 = 0; ic0 < 128; ic0 += 16) {
        __syncthreads();
        for (int f = t; f < 16 * 18 * 18; f += 256) {
            int ic = f / 324; int rem = f % 324; int row = rem / 18, col = rem % 18;
            int gy = y0 - 1 + row, gxx = x0 - 1 + col;
            float v = 0.f;
            if (gy >= 0 && gy < H_ && gxx >= 0 && gxx < W_)
                v = __bfloat162float(hb[(size_t)(ic0 + ic) * HW_ + gy * W_ + gxx]);
            in_s[ic][row * 19 + col] = v;
        }
        __syncthreads();
        for (int ic = 0; ic < 16; ic++) {
            #pragma unroll
            for (int ky = 0; ky < 3; ky++) {
                #pragma unroll
                for (int kx = 0; kx < 3; kx++) {
                    float x = in_s[ic][(r + ky) * 19 + c + kx];
                    int wk = (ic0 + ic) * 9 + ky * 3 + kx;
                    acc0 += x * w2_s[0][wk];
                    acc1 += x * w2_s[1][wk];
                }
            }
        }
    }
    int py = (y0 + r) * W_ + x0 + c;
    out[((size_t)b * 2 + 0) * HW_ + py] = acc0 + b2[0];
    out[((size_t)b * 2 + 1) * HW_ + py] = acc1 + b2[1];
}

// ---------------------------------------------------------------- launch ----
extern "C" void kernel_launch(void* const* d_in, const int* in_sizes, int n_in,
                              void* d_out, int out_size, void* d_ws, size_t ws_size,
                              hipStream_t stream)
{
    const float* cur_embed  = (const float*)d_in[0];
    const float* cur_decode = (const float*)d_in[1];
    const float* init_embed = (const float*)d_in[2];
    const float* init_seg   = (const float*)d_in[3];
    const float* prev_embed = (const float*)d_in[4];
    const float* prev_seg   = (const float*)d_in[5];
    const float* W1 = (const float*)d_in[6];
    const float* b1 = (const float*)d_in[7];
    const float* W2 = (const float*)d_in[8];
    const float* b2 = (const float*)d_in[9];
    float* out = (float*)d_out;

    char* ws = (char*)d_ws;
    bf16* hcat8 = (bf16*)ws;                          // [8][8][9604][32]
    bf16* curbf = (bf16*)ws;                          // alias (dead at memset)
    bf16* hcat1 = (bf16*)(ws + 39337984);             // [8][9604][8]
    const size_t HCAT_REGION = 40567296;
    bf16* hmid   = (bf16*)(ws + HCAT_REGION);
    bf16* fibf   = (bf16*)(ws + HCAT_REGION);         // phase-1 alias
    bf16* prevbf = (bf16*)(ws + HCAT_REGION);         // phase-2 alias (4 batches)
    float* si  = (float*)(ws + HCAT_REGION + 2621440);
    bf16* w1bf = (bf16*)(ws + 59441664);
    float* gout = (float*)(ws + 60105216);
    float* lout = (float*)(ws + 60695040);

    { int total = 81 * 128 * 32;
      w1cvt_kernel<<<(total + 255) / 256, 256, 0, stream>>>(W1, w1bf); }
    { dim3 g(144, 4, B_);
      tcur_kernel<<<g, 256, 0, stream>>>(cur_embed, curbf); }
    { int total = B_ * (C_ + 2) * KPP;
      pool_kernel<<<(total + 255) / 256, 256, 0, stream>>>(init_embed, init_seg, fibf, si); }
    { dim3 g(144, B_);
      gmap_mfma<<<g, 128, 0, stream>>>(curbf, fibf, si, gout); }
    for (int g = 0; g < 2; g++) {
        dim3 gt(144, 4, 4);
        tcur_kernel<<<gt, 256, 0, stream>>>(prev_embed + (size_t)g * 4 * C_ * HW_, prevbf);
        dim3 gl(144, 4);
        lmap_mfma<<<gl, 256, 0, stream>>>(curbf, prevbf, prev_seg, lout, g * 4);
    }
    hipMemsetAsync(ws, 0, HCAT_REGION, stream);       // zero hcat8+hcat1; curbf dead
    { dim3 g(144, 4, B_);
      pack_dec_kernel<<<g, 256, 0, stream>>>(cur_decode, hcat8); }
    { int total = B_ * HW_;
      pack_small_kernel<<<(total + 255) / 256, 256, 0, stream>>>(gout, lout, init_seg, prev_seg, hcat1); }
    { dim3 g(144, B_);
      conv1_mfma<<<g, 128, 0, stream>>>(hcat8, hcat1, w1bf, b1, hmid); }
    { dim3 g(36, B_);
      conv2_kernel<<<g, 256, 0, stream>>>(hmid, W2, b2, out); }
}

// Round 6
// 479.142 us; speedup vs baseline: 4.6208x; 1.0010x over previous
//
#include <hip/hip_runtime.h>
#include <hip/hip_bf16.h>

// Round 6: conv1 -> XCD-locality swizzle (1 batch per XCD; sequential strips reuse
//          row-overlap in-L2) + depth-3 register pipeline (4 rotating buffers).
// ws layout (61.28 MB, aliased):
//   [0, 39,337,984)           hcat8 bf16 [8][8][9604][32]   -- ALSO curbf bf16 [8][9216][256] (dead at memset)
//   [39,337,984, 40,567,296)  hcat1 bf16 [8][9604][8] (tail ch 256..263)
//   [40,567,296, 59,441,664)  hmid bf16 [8][128][9216]
//       -- phase1 alias: fibf bf16 [8][640][256] @ +0, si f32 [8][2][640] @ +2,621,440
//       -- phase2 alias: prevbf bf16 [4][9216][256] (exactly 18,874,368 B)
//   [59,441,664, 60,105,216)  W1bf bf16 [81][128][32]
//   [60,105,216, 60,695,040)  gout f32 [8][2][9216]
//   [60,695,040, 61,284,864)  lout f32 [8][2][9216]

typedef __hip_bfloat16 bf16;
typedef __attribute__((ext_vector_type(8))) short short8;
typedef __attribute__((ext_vector_type(4))) float f32x4;

constexpr int B_  = 8;
constexpr int C_  = 256;
constexpr int H_  = 96;
constexpr int W_  = 96;
constexpr int HW_ = H_ * W_;       // 9216
constexpr int PW_ = 24;
constexpr int KP_ = 576;
constexpr int KPP = 640;
constexpr int HP_ = 98;
constexpr int HPW = HP_ * HP_;     // 9604
constexpr int C1O = 128;
constexpr int CHK = HPW * 32;      // 307,328 elems per 32-ch chunk

__device__ __forceinline__ unsigned short bfb(float f) {
    bf16 h = __float2bfloat16(f);
    return *reinterpret_cast<unsigned short*>(&h);
}

// ------------------------------------------------------------ W1 convert ----
__global__ __launch_bounds__(256)
void w1cvt_kernel(const float* __restrict__ W1, bf16* __restrict__ w1bf)
{
    int idx = blockIdx.x * 256 + threadIdx.x;
    if (idx >= 81 * 128 * 32) return;
    int ic = idx & 31;
    int oc = (idx >> 5) & 127;
    int ks = idx >> 12;
    int tap = ks / 9, icc = ks % 9;
    int icg = icc * 32 + ic;
    float v = (icg < 264) ? W1[((size_t)oc * 264 + icg) * 9 + tap] : 0.f;
    w1bf[idx] = __float2bfloat16(v);
}

// ------------------------------------------------------- NCHW->NHWC bf16 ----
__global__ __launch_bounds__(256)
void tcur_kernel(const float* __restrict__ cur, bf16* __restrict__ curbf)
{
    __shared__ float tile[64][68];
    int b = blockIdx.z, c0 = blockIdx.y * 64, p0 = blockIdx.x * 64;
    int t = threadIdx.x;
    const float* src = cur + ((size_t)b * C_ + c0) * HW_ + p0;
    #pragma unroll
    for (int it = 0; it < 4; it++) {
        int f = t + it * 256;
        int cl = f >> 4, p4 = (f & 15) * 4;
        float4 v = *reinterpret_cast<const float4*>(src + (size_t)cl * HW_ + p4);
        *reinterpret_cast<float4*>(&tile[cl][p4]) = v;
    }
    __syncthreads();
    bf16* dst = curbf + ((size_t)b * HW_ + p0) * 256 + c0;
    #pragma unroll
    for (int it = 0; it < 4; it++) {
        int f = t + it * 256;
        int pl = f >> 4, c4 = (f & 15) * 4;
        ushort4 u;
        u.x = bfb(tile[c4 + 0][pl]); u.y = bfb(tile[c4 + 1][pl]);
        u.z = bfb(tile[c4 + 2][pl]); u.w = bfb(tile[c4 + 3][pl]);
        *reinterpret_cast<ushort4*>(dst + (size_t)pl * 256 + c4) = u;
    }
}

// ---------------------------------------------------------------- pool ----
__global__ __launch_bounds__(256)
void pool_kernel(const float* __restrict__ init_embed,
                 const float* __restrict__ init_seg,
                 bf16* __restrict__ fibf, float* __restrict__ si)
{
    int idx = blockIdx.x * 256 + threadIdx.x;
    int total = B_ * (C_ + 2) * KPP;
    if (idx >= total) return;
    int k  = idx % KPP;
    int ch = (idx / KPP) % (C_ + 2);
    int b  = idx / (KPP * (C_ + 2));
    float s = 0.f;
    if (k < KP_) {
        int ph = k / PW_, pw = k % PW_;
        const float* src = (ch < C_)
            ? (init_embed + (((size_t)b * C_ + ch) * H_ + ph * 4) * W_ + pw * 4)
            : (init_seg   + (((size_t)b * 2 + (ch - C_)) * H_ + ph * 4) * W_ + pw * 4);
        #pragma unroll
        for (int r = 0; r < 4; r++) {
            float4 v = *reinterpret_cast<const float4*>(src + r * W_);
            s += v.x + v.y + v.z + v.w;
        }
        s *= (1.f / 16.f);
    }
    if (ch < C_) fibf[((size_t)b * KPP + k) * C_ + ch] = __float2bfloat16(s);
    else         si[(size_t)b * 2 * KPP + (ch - C_) * KPP + k] = s;
}

// ---------------------------------------------------------------- gmap ----
__global__ __launch_bounds__(128)
void gmap_mfma(const bf16* __restrict__ curbf, const bf16* __restrict__ fibf,
               const float* __restrict__ si, float* __restrict__ gout)
{
    __shared__ float bred[2][2][64];
    int b = blockIdx.y;
    int p0 = blockIdx.x * 64;
    int t = threadIdx.x, lane = t & 63, wm = t >> 6;
    int l15 = lane & 15, lk = lane >> 4;
    const bf16* cb = curbf + (size_t)b * HW_ * 256;
    const bf16* fb = fibf + (size_t)b * KPP * 256;
    const float* sib = si + (size_t)b * 2 * KPP;
    size_t bo[4];
    #pragma unroll
    for (int nt = 0; nt < 4; nt++)
        bo[nt] = (size_t)(p0 + nt * 16 + l15) * 256 + lk * 8;
    float best[2][4];
    #pragma unroll
    for (int s = 0; s < 2; s++)
        #pragma unroll
        for (int nt = 0; nt < 4; nt++) best[s][nt] = -INFINITY;

    for (int ch = 0; ch < 5; ch++) {
        int kp0 = ch * 128;
        f32x4 acc[4][4] = {};
        for (int kc = 0; kc < 8; kc++) {
            short8 a[4], bbf[4];
            #pragma unroll
            for (int mt = 0; mt < 4; mt++)
                a[mt] = *reinterpret_cast<const short8*>(
                    fb + (size_t)(kp0 + wm * 64 + mt * 16 + l15) * 256 + kc * 32 + lk * 8);
            #pragma unroll
            for (int nt = 0; nt < 4; nt++)
                bbf[nt] = *reinterpret_cast<const short8*>(cb + bo[nt] + kc * 32);
            #pragma unroll
            for (int mt = 0; mt < 4; mt++)
                #pragma unroll
                for (int nt = 0; nt < 4; nt++)
                    acc[mt][nt] = __builtin_amdgcn_mfma_f32_16x16x32_bf16(
                        a[mt], bbf[nt], acc[mt][nt], 0, 0, 0);
        }
        #pragma unroll
        for (int mt = 0; mt < 4; mt++) {
            int rb = kp0 + wm * 64 + mt * 16 + lk * 4;
            float4 s0 = *reinterpret_cast<const float4*>(sib + rb);
            float4 s1 = *reinterpret_cast<const float4*>(sib + KPP + rb);
            const float* s0p = reinterpret_cast<const float*>(&s0);
            const float* s1p = reinterpret_cast<const float*>(&s1);
            #pragma unroll
            for (int nt = 0; nt < 4; nt++)
                #pragma unroll
                for (int r = 0; r < 4; r++) {
                    float v = acc[mt][nt][r];
                    best[0][nt] = fmaxf(best[0][nt], v * s0p[r]);
                    best[1][nt] = fmaxf(best[1][nt], v * s1p[r]);
                }
        }
    }
    #pragma unroll
    for (int s = 0; s < 2; s++)
        #pragma unroll
        for (int nt = 0; nt < 4; nt++) {
            float v = best[s][nt];
            v = fmaxf(v, __shfl_xor(v, 16));
            v = fmaxf(v, __shfl_xor(v, 32));
            if (lk == 0) bred[wm][s][nt * 16 + l15] = v;
        }
    __syncthreads();
    if (t < 128) {
        int s = t >> 6, pxl = t & 63;
        gout[((size_t)b * 2 + s) * HW_ + p0 + pxl] = fmaxf(bred[0][s][pxl], bred[1][s][pxl]);
    }
}

// ---------------------------------------------------------------- lmap ----
__global__ __launch_bounds__(256)
void lmap_mfma(const bf16* __restrict__ curbf, const bf16* __restrict__ prevbf,
               const float* __restrict__ prev_seg, float* __restrict__ lout, int b0)
{
    constexpr int GSTR = 257;
    constexpr int SEGB = 64 * GSTR;
    constexpr int REDB = SEGB + 512;
    __shared__ float gl[REDB + 256];
    int b = b0 + blockIdx.y;
    const bf16* pb = prevbf + (size_t)blockIdx.y * HW_ * 256;
    const bf16* cb = curbf + (size_t)b * HW_ * 256;
    int tile = blockIdx.x;
    int ty0 = (tile / 12) * 8, tx0 = (tile % 12) * 8;
    int t = threadIdx.x, lane = t & 63, wq = t >> 6;
    int l15 = lane & 15, lk = lane >> 4;

    size_t aoff[4];
    #pragma unroll
    for (int mt = 0; mt < 4; mt++) {
        int m = mt * 16 + l15;
        int gpx = (ty0 + (m >> 3)) * W_ + tx0 + (m & 7);
        aoff[mt] = (size_t)gpx * 256 + lk * 8;
    }
    bool pred[4];
    size_t boff[4];
    int gx = tx0 - 4 + l15;
    bool colok = (gx >= 0) && (gx < W_);
    #pragma unroll
    for (int nt = 0; nt < 4; nt++) {
        int gy = ty0 - 4 + wq * 4 + nt;
        pred[nt] = colok && (gy >= 0) && (gy < H_);
        boff[nt] = pred[nt] ? ((size_t)(gy * W_ + gx) * 256 + lk * 8) : 0;
    }

    f32x4 acc[4][4] = {};
    const short8 Z8 = {0, 0, 0, 0, 0, 0, 0, 0};
    for (int kc = 0; kc < 8; kc++) {
        short8 a[4], bb[4];
        #pragma unroll
        for (int mt = 0; mt < 4; mt++)
            a[mt] = *reinterpret_cast<const short8*>(cb + aoff[mt] + kc * 32);
        #pragma unroll
        for (int nt = 0; nt < 4; nt++) {
            short8 v = Z8;
            if (pred[nt]) v = *reinterpret_cast<const short8*>(pb + boff[nt] + kc * 32);
            bb[nt] = v;
        }
        #pragma unroll
        for (int mt = 0; mt < 4; mt++)
            #pragma unroll
            for (int nt = 0; nt < 4; nt++)
                acc[mt][nt] = __builtin_amdgcn_mfma_f32_16x16x32_bf16(
                    a[mt], bb[nt], acc[mt][nt], 0, 0, 0);
    }
    #pragma unroll
    for (int mt = 0; mt < 4; mt++)
        #pragma unroll
        for (int nt = 0; nt < 4; nt++)
            #pragma unroll
            for (int r = 0; r < 4; r++)
                gl[(mt * 16 + lk * 4 + r) * GSTR + wq * 64 + nt * 16 + l15] = acc[mt][nt][r];
    #pragma unroll
    for (int it = 0; it < 2; it++) {
        int f = t + it * 256;
        int s = f >> 8, wp = f & 255;
        int wy = wp >> 4, wx = wp & 15;
        int gy = ty0 - 4 + wy, gxx = tx0 - 4 + wx;
        float v = 0.f;
        if (gy >= 0 && gy < H_ && gxx >= 0 && gxx < W_)
            v = prev_seg[((size_t)b * 2 + s) * HW_ + gy * W_ + gxx] * (1.f / 256.f);
        gl[SEGB + f] = v;
    }
    __syncthreads();
    {
        int m = t & 63;
        int sh = t >> 6;
        int s = sh >> 1, hh = sh & 1;
        int py = m >> 3, lx = m & 7;
        const float* gr = gl + m * GSTR;
        const float* sr = gl + SEGB + s * 256;
        float mx = -INFINITY;
        int wr0 = hh * 5, wr1 = hh ? 9 : 5;
        for (int wr = wr0; wr < wr1; ++wr) {
            int base = (py + wr) * 16 + lx;
            #pragma unroll
            for (int wc = 0; wc < 9; ++wc)
                mx = fmaxf(mx, gr[base + wc] * sr[base + wc]);
        }
        gl[REDB + sh * 64 + m] = mx;
    }
    __syncthreads();
    if (t < 128) {
        int s = t >> 6, m = t & 63;
        float v = fmaxf(gl[REDB + (s * 2 + 0) * 64 + m], gl[REDB + (s * 2 + 1) * 64 + m]);
        int gpx = (ty0 + (m >> 3)) * W_ + tx0 + (m & 7);
        lout[((size_t)b * 2 + s) * HW_ + gpx] = v;
    }
}

// ---------------------------------------------------------------- packs ----
__global__ __launch_bounds__(256)
void pack_dec_kernel(const float* __restrict__ dec, bf16* __restrict__ hcat8)
{
    __shared__ float tile[64][68];
    int b = blockIdx.z, c0 = blockIdx.y * 64, p0 = blockIdx.x * 64;
    int t = threadIdx.x;
    const float* src = dec + ((size_t)b * C_ + c0) * HW_ + p0;
    #pragma unroll
    for (int it = 0; it < 4; it++) {
        int f = t + it * 256;
        int cl = f >> 4, p4 = (f & 15) * 4;
        float4 v = *reinterpret_cast<const float4*>(src + (size_t)cl * HW_ + p4);
        *reinterpret_cast<float4*>(&tile[cl][p4]) = v;
    }
    __syncthreads();
    #pragma unroll
    for (int it = 0; it < 4; it++) {
        int f = t + it * 256;
        int pl = f >> 4, c4 = (f & 15) * 4;
        int p = p0 + pl;
        int y = p / 96, x = p % 96;
        int pos = (y + 1) * HP_ + x + 1;
        int ch = c0 + c4;
        ushort4 u;
        u.x = bfb(tile[c4 + 0][pl]); u.y = bfb(tile[c4 + 1][pl]);
        u.z = bfb(tile[c4 + 2][pl]); u.w = bfb(tile[c4 + 3][pl]);
        bf16* dst = hcat8 + ((size_t)b * 8 + (ch >> 5)) * CHK + (size_t)pos * 32 + (ch & 31);
        *reinterpret_cast<ushort4*>(dst) = u;
    }
}

__global__ __launch_bounds__(256)
void pack_small_kernel(const float* __restrict__ gout,
                       const float* __restrict__ lout,
                       const float* __restrict__ init_seg,
                       const float* __restrict__ prev_seg,
                       bf16* __restrict__ hcat1)
{
    int idx = blockIdx.x * 256 + threadIdx.x;
    if (idx >= B_ * HW_) return;
    int b = idx / HW_, p = idx % HW_;
    int y = p / 96, x = p % 96;
    int pos = (y + 1) * HP_ + x + 1;
    bf16* dst = hcat1 + ((size_t)b * HPW + pos) * 8;
    float g0 = gout[((size_t)b * 2 + 0) * HW_ + p];
    float g1 = gout[((size_t)b * 2 + 1) * HW_ + p];
    float i0 = init_seg[((size_t)b * 2 + 0) * HW_ + p];
    float i1 = init_seg[((size_t)b * 2 + 1) * HW_ + p];
    float l0 = lout[((size_t)b * 2 + 0) * HW_ + p];
    float l1 = lout[((size_t)b * 2 + 1) * HW_ + p];
    float q0 = prev_seg[((size_t)b * 2 + 0) * HW_ + p];
    float q1 = prev_seg[((size_t)b * 2 + 1) * HW_ + p];
    ushort4 u; u.x = bfb(g0); u.y = bfb(g1); u.z = bfb(i0); u.w = bfb(i1);
    *reinterpret_cast<ushort4*>(dst) = u;
    ushort4 u2; u2.x = bfb(l0); u2.y = bfb(l1); u2.z = bfb(q0); u2.w = bfb(q1);
    *reinterpret_cast<ushort4*>(dst + 4) = u2;
}

// ---------------------------------------------------------------- conv1 ----
// No-LDS implicit GEMM over chunked NHWC, XCD-locality swizzle (1 batch/XCD,
// sequential strips), depth-3 register pipeline (4 rotating frag buffers).
__global__ __launch_bounds__(128)
void conv1_mfma(const bf16* __restrict__ hcat8, const bf16* __restrict__ hcat1,
                const bf16* __restrict__ w1bf, const float* __restrict__ b1,
                bf16* __restrict__ hmid)
{
    int gid = blockIdx.x;              // 1152; XCD ~= gid % 8
    int b = gid & 7;                   // one batch per XCD
    int p0 = (gid >> 3) * 64;          // sequential strips within XCD
    int t = threadIdx.x, lane = t & 63, wm = t >> 6;
    int l15 = lane & 15, lk = lane >> 4;
    const bf16* hb8 = hcat8 + (size_t)b * 8 * CHK;
    const bf16* hb1 = hcat1 + (size_t)b * HPW * 8;
    int pos[4];
    #pragma unroll
    for (int nt = 0; nt < 4; nt++) {
        int p = p0 + nt * 16 + l15;
        pos[nt] = (p / 96) * HP_ + (p % 96);
    }
    int aocb = (wm * 64 + l15) * 32 + lk * 8;
    f32x4 acc[4][4] = {};
    short8 abuf[4][4], bbuf[4][4];
    const short8 Z8 = {0, 0, 0, 0, 0, 0, 0, 0};

    auto LOAD = [&](int s, int ph) {
        int tap = s / 9, icc = s % 9;
        int toff = (tap / 3) * HP_ + (tap % 3);
        const bf16* wp = w1bf + (size_t)s * 4096;
        #pragma unroll
        for (int mt = 0; mt < 4; mt++)
            abuf[ph][mt] = *reinterpret_cast<const short8*>(wp + aocb + mt * 512);
        if (icc < 8) {
            const bf16* cp = hb8 + (size_t)icc * CHK;
            #pragma unroll
            for (int nt = 0; nt < 4; nt++)
                bbuf[ph][nt] = *reinterpret_cast<const short8*>(
                    cp + (size_t)(pos[nt] + toff) * 32 + lk * 8);
        } else {
            #pragma unroll
            for (int nt = 0; nt < 4; nt++) {
                short8 v = *reinterpret_cast<const short8*>(
                    hb1 + (size_t)(pos[nt] + toff) * 8);
                bbuf[ph][nt] = (lk == 0) ? v : Z8;
            }
        }
    };

    LOAD(0, 0);
    LOAD(1, 1);
    LOAD(2, 2);
    #pragma unroll
    for (int s = 0; s < 81; ++s) {
        int ph = s & 3;
        if (s + 3 < 81) LOAD(s + 3, (s + 3) & 3);
        #pragma unroll
        for (int mt = 0; mt < 4; mt++)
            #pragma unroll
            for (int nt = 0; nt < 4; nt++)
                acc[mt][nt] = __builtin_amdgcn_mfma_f32_16x16x32_bf16(
                    abuf[ph][mt], bbuf[ph][nt], acc[mt][nt], 0, 0, 0);
    }

    bf16* hm = hmid + (size_t)b * C1O * HW_;
    #pragma unroll
    for (int mt = 0; mt < 4; mt++) {
        int ocb = wm * 64 + mt * 16 + lk * 4;
        float4 bias = *reinterpret_cast<const float4*>(b1 + ocb);
        const float* bp = reinterpret_cast<const float*>(&bias);
        #pragma unroll
        for (int nt = 0; nt < 4; nt++) {
            int p = p0 + nt * 16 + l15;
            #pragma unroll
            for (int r = 0; r < 4; r++) {
                float v = fmaxf(acc[mt][nt][r] + bp[r], 0.f);
                hm[(size_t)(ocb + r) * HW_ + p] = __float2bfloat16(v);
            }
        }
    }
}

// ---------------------------------------------------------------- conv2 ----
__global__ __launch_bounds__(256)
void conv2_kernel(const bf16* __restrict__ hmid,
                  const float* __restrict__ W2,
                  const float* __restrict__ b2,
                  float* __restrict__ out)
{
    __shared__ float in_s[16][18 * 19];
    __shared__ float w2_s[2][128 * 9];
    int b = blockIdx.y;
    int tile = blockIdx.x;
    int y0 = (tile / 6) * 16, x0 = (tile % 6) * 16;
    int t = threadIdx.x;
    int r = t >> 4, c = t & 15;
    for (int f = t; f < 2 * 128 * 9; f += 256) w2_s[f / 1152][f % 1152] = W2[f];
    float acc0 = 0.f, acc1 = 0.f;
    const bf16* hb = hmid + (size_t)b * C1O * HW_;
    for (int ic0 = 0; ic0 < 128; ic0 += 16) {
        __syncthreads();
        for (int f = t; f < 16 * 18 * 18; f += 256) {
            int ic = f / 324; int rem = f % 324; int row = rem / 18, col = rem % 18;
            int gy = y0 - 1 + row, gxx = x0 - 1 + col;
            float v = 0.f;
            if (gy >= 0 && gy < H_ && gxx >= 0 && gxx < W_)
                v = __bfloat162float(hb[(size_t)(ic0 + ic) * HW_ + gy * W_ + gxx]);
            in_s[ic][row * 19 + col] = v;
        }
        __syncthreads();
        for (int ic = 0; ic < 16; ic++) {
            #pragma unroll
            for (int ky = 0; ky < 3; ky++) {
                #pragma unroll
                for (int kx = 0; kx < 3; kx++) {
                    float x = in_s[ic][(r + ky) * 19 + c + kx];
                    int wk = (ic0 + ic) * 9 + ky * 3 + kx;
                    acc0 += x * w2_s[0][wk];
                    acc1 += x * w2_s[1][wk];
                }
            }
        }
    }
    int py = (y0 + r) * W_ + x0 + c;
    out[((size_t)b * 2 + 0) * HW_ + py] = acc0 + b2[0];
    out[((size_t)b * 2 + 1) * HW_ + py] = acc1 + b2[1];
}

// ---------------------------------------------------------------- launch ----
extern "C" void kernel_launch(void* const* d_in, const int* in_sizes, int n_in,
                              void* d_out, int out_size, void* d_ws, size_t ws_size,
                              hipStream_t stream)
{
    const float* cur_embed  = (const float*)d_in[0];
    const float* cur_decode = (const float*)d_in[1];
    const float* init_embed = (const float*)d_in[2];
    const float* init_seg   = (const float*)d_in[3];
    const float* prev_embed = (const float*)d_in[4];
    const float* prev_seg   = (const float*)d_in[5];
    const float* W1 = (const float*)d_in[6];
    const float* b1 = (const float*)d_in[7];
    const float* W2 = (const float*)d_in[8];
    const float* b2 = (const float*)d_in[9];
    float* out = (float*)d_out;

    char* ws = (char*)d_ws;
    bf16* hcat8 = (bf16*)ws;                          // [8][8][9604][32]
    bf16* curbf = (bf16*)ws;                          // alias (dead at memset)
    bf16* hcat1 = (bf16*)(ws + 39337984);             // [8][9604][8]
    const size_t HCAT_REGION = 40567296;
    bf16* hmid   = (bf16*)(ws + HCAT_REGION);
    bf16* fibf   = (bf16*)(ws + HCAT_REGION);         // phase-1 alias
    bf16* prevbf = (bf16*)(ws + HCAT_REGION);         // phase-2 alias (4 batches)
    float* si  = (float*)(ws + HCAT_REGION + 2621440);
    bf16* w1bf = (bf16*)(ws + 59441664);
    float* gout = (float*)(ws + 60105216);
    float* lout = (float*)(ws + 60695040);

    { int total = 81 * 128 * 32;
      w1cvt_kernel<<<(total + 255) / 256, 256, 0, stream>>>(W1, w1bf); }
    { dim3 g(144, 4, B_);
      tcur_kernel<<<g, 256, 0, stream>>>(cur_embed, curbf); }
    { int total = B_ * (C_ + 2) * KPP;
      pool_kernel<<<(total + 255) / 256, 256, 0, stream>>>(init_embed, init_seg, fibf, si); }
    { dim3 g(144, B_);
      gmap_mfma<<<g, 128, 0, stream>>>(curbf, fibf, si, gout); }
    for (int g = 0; g < 2; g++) {
        dim3 gt(144, 4, 4);
        tcur_kernel<<<gt, 256, 0, stream>>>(prev_embed + (size_t)g * 4 * C_ * HW_, prevbf);
        dim3 gl(144, 4);
        lmap_mfma<<<gl, 256, 0, stream>>>(curbf, prevbf, prev_seg, lout, g * 4);
    }
    hipMemsetAsync(ws, 0, HCAT_REGION, stream);       // zero hcat8+hcat1; curbf dead
    { dim3 g(144, 4, B_);
      pack_dec_kernel<<<g, 256, 0, stream>>>(cur_decode, hcat8); }
    { int total = B_ * HW_;
      pack_small_kernel<<<(total + 255) / 256, 256, 0, stream>>>(gout, lout, init_seg, prev_seg, hcat1); }
    { conv1_mfma<<<1152, 128, 0, stream>>>(hcat8, hcat1, w1bf, b1, hmid); }
    { dim3 g(36, B_);
      conv2_kernel<<<g, 256, 0, stream>>>(hmid, W2, b2, out); }
}